// Round 16
// baseline (175.413 us; speedup 1.0000x reference)
//
#include <hip/hip_runtime.h>
#include <math.h>

// ASFF_2: N=8, C1=256, C2=512, H=64, W=64, low-res 32x32.
// CARAFE-commutation: u = CARAFE(z)+b_up with z = w_up@in2 (low-res GEMM);
// v2 = CARAFE(zw)+c2 with zw = w_l2@z, c2 = w_l2@b_up.
//  in2t: input2 -> in2T bf16 [n][1024][512]
//  down_mfma: ktT = bf16T(w_down @ in2T + b_down) [n][34*34][128] padded
//  enc_mfma -> kt2 ; softmax -> maskb
//  zgemm: zbfT = bf16(w_up @ in2T) [n][1024][256]
//  zw: zwT[n][1024][8] = w_l2 @ z
//  fuse_weights: v1 = w_l1@i1, v2 = CARAFE(zw)+c2 -> lw0[n][4096]
//  carafe_blend: u=CARAFE(z)+b_up, blend with i1 -> fusedT bf16 [66x66][256]
//  K7: m97 GEMM, post-barrier 3-phase-deep A staging (4 bufs), exact vmcnt
//      ladder {8/4/2/0} from in-order retirement accounting.

#define EPS 1e-5f
typedef unsigned short u16;
typedef __attribute__((ext_vector_type(8))) __bf16 bf16x8;
typedef __attribute__((ext_vector_type(4))) float f32x4;

#define VMCNT(N) asm volatile("s_waitcnt vmcnt(" #N ")" ::: "memory")

__device__ inline u16 f2bf(float x) {
    union { float f; unsigned u; } v; v.f = x;
    unsigned r = v.u + 0x7FFF + ((v.u >> 16) & 1);
    return (u16)(r >> 16);
}
__device__ inline float bf2f(u16 x) {
    union { unsigned u; float f; } v; v.u = (unsigned)x << 16; return v.f;
}

// ---------------- in2t: transpose-cast input2 [512][1024] -> in2T bf16 [q][512] ----------------
__global__ __launch_bounds__(256) void in2t_kernel(
    const float* __restrict__ src0, u16* __restrict__ dst)
{
    __shared__ u16 lds[32 * 514];
    const int n = blockIdx.y;
    const int p0 = blockIdx.x * 32;
    const int tid = threadIdx.x;
    {
        const int w = tid & 31;
        const int chunk = tid >> 5;
        const float* src = src0 + (long)n * 512 * 1024 + p0 + w;
        for (int ci = chunk * 64; ci < chunk * 64 + 64; ++ci)
            lds[w * 514 + ci] = f2bf(src[(long)ci * 1024]);
    }
    __syncthreads();
    const int px = tid >> 3;
    const int qd = tid & 7;
    u16* drow = dst + ((long)n * 1024 + p0 + px) * 512;
    const u16* lrow = lds + px * 514;
#pragma unroll
    for (int j = 0; j < 32; ++j) {
        int off = j * 16 + qd * 2;
        *(unsigned*)(drow + off) = *(const unsigned*)(lrow + off);
    }
}

// ---------------- staging macros ----------------
#define STAGE_A(dstp, t, kx)                                                         \
    {                                                                                \
        const u16* Abase = A + ((long)(t) * 256 + rowBase) * KCC + (kx) * 32;        \
        _Pragma("unroll")                                                            \
        for (int ii = 0; ii < 2; ++ii) {                                             \
            int f = ii * 256 + tid;                                                  \
            int r = f >> 2, uu = f & 3;                                              \
            __builtin_amdgcn_global_load_lds(                                        \
                (const __attribute__((address_space(1))) void*)                      \
                    (Abase + (long)r * KCC + ((uu ^ ((r >> 1) & 3)) << 3)),          \
                (__attribute__((address_space(3))) void*)((dstp) + f * 8),           \
                16, 0, 0);                                                           \
        }                                                                            \
    }

#define STAGE_B(dstp, kx)                                                            \
    {                                                                                \
        const u16* Bbase = Bn + (long)g0 * KCC + (kx) * 32;                          \
        for (int f = tid; f < BUNITS; f += 256) {                                    \
            int r = f >> 2, uu = f & 3;                                              \
            __builtin_amdgcn_global_load_lds(                                        \
                (const __attribute__((address_space(1))) void*)                      \
                    (Bbase + (long)r * KCC + ((uu ^ ((r >> 1) & 3)) << 3)),          \
                (__attribute__((address_space(3))) void*)((dstp) + f * 8),           \
                16, 0, 0);                                                           \
        }                                                                            \
    }

// ---------------- lowres GEMM core (zgemm / down_mfma): KCC=512, 16 phases ----------------
#define LOWRES_GEMM_BODY(MROWS)                                                      \
    constexpr int KCC = 512;                                                         \
    constexpr int BUNITS = 512;                                                      \
    __shared__ __align__(16) u16 lsA[3][128 * 32];                                   \
    __shared__ __align__(16) u16 lsB[3][128 * 32];                                   \
    const int n = blockIdx.z;                                                        \
    const u16* Bn = B + (long)n * 1024 * 512;                                        \
    const int tid = threadIdx.x;                                                     \
    const int lane = tid & 63;                                                       \
    const int wid = tid >> 6;                                                        \
    const int mw = wid >> 1, nw = wid & 1;                                           \
    const int lr = lane & 15, lk = lane >> 4;                                        \
    const int rowBase = blockIdx.y * 128;                                            \
    const int colBase = blockIdx.x * 128;                                            \
    const int g0 = colBase;                                                          \
    STAGE_A(lsA[0], 0, 0); STAGE_B(lsB[0], 0);                                       \
    STAGE_A(lsA[1], 0, 1); STAGE_B(lsB[1], 1);                                       \
    const int aswz = (lk ^ ((lr >> 1) & 3)) << 3;                                    \
    int aoff[4];                                                                     \
    _Pragma("unroll")                                                                \
    for (int mf = 0; mf < 4; ++mf)                                                   \
        aoff[mf] = (mw * 64 + mf * 16 + lr) * 32 + aswz;                             \
    f32x4 acc[4][4] = {};                                                            \
    for (int kx = 0; kx < 16; ++kx) {                                                \
        if (kx == 15) { VMCNT(0); } else { VMCNT(4); }                               \
        __builtin_amdgcn_s_barrier();                                                \
        asm volatile("" ::: "memory");                                               \
        if (kx + 2 < 16) {                                                           \
            STAGE_A(lsA[(kx + 2) % 3], 0, kx + 2);                                   \
            STAGE_B(lsB[(kx + 2) % 3], kx + 2);                                      \
        }                                                                            \
        const u16* la = lsA[kx % 3];                                                 \
        const u16* lb = lsB[kx % 3];                                                 \
        bf16x8 af[4], bfr[4];                                                        \
        _Pragma("unroll")                                                            \
        for (int mf = 0; mf < 4; ++mf)                                               \
            af[mf] = *(const bf16x8*)(la + aoff[mf]);                                \
        const int rb = nw * 64 + lr;                                                 \
        const int bswz = (lk ^ ((rb >> 1) & 3)) << 3;                                \
        _Pragma("unroll")                                                            \
        for (int nf = 0; nf < 4; ++nf)                                               \
            bfr[nf] = *(const bf16x8*)(lb + (rb + nf * 16) * 32 + bswz);             \
        _Pragma("unroll")                                                            \
        for (int mf = 0; mf < 4; ++mf)                                               \
            _Pragma("unroll")                                                        \
            for (int nf = 0; nf < 4; ++nf)                                           \
                acc[mf][nf] = __builtin_amdgcn_mfma_f32_16x16x32_bf16(               \
                    af[mf], bfr[nf], acc[mf][nf], 0, 0, 0);                          \
    }

// ---------------- zgemm: zbfT = bf16(w_up @ in2T)  [n][1024][256] ----------------
__global__ __launch_bounds__(256, 2) void zgemm_kernel(
    const u16* __restrict__ A,      // wupT [256][512]
    const u16* __restrict__ B,      // in2T [n][1024][512]
    u16* __restrict__ Z)            // zbfT [n][1024][256]
{
    LOWRES_GEMM_BODY(256)
    u16* Zn = Z + (long)n * 1024 * 256;
#pragma unroll
    for (int mf = 0; mf < 4; ++mf) {
        const int co0 = rowBase + mw * 64 + mf * 16 + lk * 4;
#pragma unroll
        for (int nf = 0; nf < 4; ++nf) {
            const int col = colBase + nw * 64 + nf * 16 + lr;
            unsigned lo = (unsigned)f2bf(acc[mf][nf][0]) |
                          ((unsigned)f2bf(acc[mf][nf][1]) << 16);
            unsigned hi = (unsigned)f2bf(acc[mf][nf][2]) |
                          ((unsigned)f2bf(acc[mf][nf][3]) << 16);
            *(uint2*)(Zn + (long)col * 256 + co0) = make_uint2(lo, hi);
        }
    }
}

// ---------------- down_mfma: ktT = bf16T(w_down @ in2T + b_down), padded 34x34 ----------------
__global__ __launch_bounds__(256, 2) void down_mfma_kernel(
    const u16* __restrict__ A,      // wdT [128][512]
    const u16* __restrict__ B,      // in2T [n][1024][512]
    const float* __restrict__ bias, u16* __restrict__ ktT)
{
    LOWRES_GEMM_BODY(128)
    u16* Kn = ktT + (long)n * 1156 * 128;
#pragma unroll
    for (int mf = 0; mf < 4; ++mf) {
        const int co0 = mw * 64 + mf * 16 + lk * 4;     // 0..124
        float b0 = bias[co0], b1 = bias[co0 + 1], b2 = bias[co0 + 2], b3 = bias[co0 + 3];
#pragma unroll
        for (int nf = 0; nf < 4; ++nf) {
            const int col = colBase + nw * 64 + nf * 16 + lr;   // 0..1023
            const int pr = ((col >> 5) + 1) * 34 + (col & 31) + 1;
            unsigned lo = (unsigned)f2bf(acc[mf][nf][0] + b0) |
                          ((unsigned)f2bf(acc[mf][nf][1] + b1) << 16);
            unsigned hi = (unsigned)f2bf(acc[mf][nf][2] + b2) |
                          ((unsigned)f2bf(acc[mf][nf][3] + b3) << 16);
            *(uint2*)(Kn + (long)pr * 128 + co0) = make_uint2(lo, hi);
        }
    }
}

// ---------------- enc_mfma: encoder conv as 9-tap shifted MFMA GEMM ----------------
__global__ __launch_bounds__(64) void enc_mfma_kernel(
    const u16* __restrict__ A, const u16* __restrict__ B,
    const float* __restrict__ bias, float* __restrict__ C)
{
    const int n = blockIdx.y;
    const int lane = threadIdx.x;
    const int lr = lane & 15, lk = lane >> 4;
    const int p = blockIdx.x * 16 + lr;
    const int pr = ((p >> 5) + 1) * 34 + (p & 31) + 1;
    const u16* Bn = B + (long)n * 1156 * 128;
    const int bOff = pr * 128 + lk * 8;
    f32x4 acc[3] = {};
    for (int t = 0; t < 9; ++t) {
        const u16* At = A + t * 8192;
        const int btap = ((t / 3 - 1) * 34 + (t % 3 - 1)) * 128;
#pragma unroll
        for (int k0 = 0; k0 < 128; k0 += 32) {
            bf16x8 bf = *(const bf16x8*)(Bn + bOff + btap + k0);
#pragma unroll
            for (int mf = 0; mf < 3; ++mf) {
                bf16x8 af = *(const bf16x8*)(At + (mf * 16 + lr) * 128 + lk * 8 + k0);
                acc[mf] = __builtin_amdgcn_mfma_f32_16x16x32_bf16(af, bf, acc[mf], 0, 0, 0);
            }
        }
    }
    float* Cn = C + (long)n * 36 * 1024;
#pragma unroll
    for (int mf = 0; mf < 3; ++mf)
#pragma unroll
        for (int reg = 0; reg < 4; ++reg) {
            int co = mf * 16 + lk * 4 + reg;
            if (co < 36)
                Cn[(long)co * 1024 + p] = acc[mf][reg] + bias[co];
        }
}

// ---------------- softmax over k=9 ----------------
__global__ __launch_bounds__(256) void mask_softmax_kernel(
    const float* __restrict__ kt2, float* __restrict__ mask)
{
    int gid = blockIdx.x * 256 + threadIdx.x;   // N*1024*4
    int q = gid & 3;
    int p = (gid >> 2) & 1023;
    int n = gid >> 12;
    float s[9];
    float mx = -1e30f;
#pragma unroll
    for (int k = 0; k < 9; ++k) {
        s[k] = kt2[(long)(n * 36 + k * 4 + q) * 1024 + p];
        mx = fmaxf(mx, s[k]);
    }
    float sum = 0.f;
#pragma unroll
    for (int k = 0; k < 9; ++k) { s[k] = expf(s[k] - mx); sum += s[k]; }
    float inv = 1.f / sum;
    float* mp = mask + (long)(n * 1024 + p) * 36 + q;
#pragma unroll
    for (int k = 0; k < 9; ++k) mp[k * 4] = s[k] * inv;
}

// ---------------- zw: one wave per low-res pixel, butterfly reduce ----------------
__global__ __launch_bounds__(256) void zw_kernel(
    const u16* __restrict__ zbfT, const float* __restrict__ wl2T,
    float* __restrict__ zwT)
{
    const int Q = (blockIdx.x * 256 + threadIdx.x) >> 6;   // 0..8191
    const int lane = threadIdx.x & 63;
    const int ci0 = lane * 4;
    uint2 v = *(const uint2*)(zbfT + (long)Q * 256 + ci0);
    float c[4] = { bf2f((u16)(v.x & 0xffff)), bf2f((u16)(v.x >> 16)),
                   bf2f((u16)(v.y & 0xffff)), bf2f((u16)(v.y >> 16)) };
    float s[8] = {};
#pragma unroll
    for (int t = 0; t < 4; ++t) {
        const float* wr = wl2T + (ci0 + t) * 8;
        float4 wa = *(const float4*)wr;
        float4 wb = *(const float4*)(wr + 4);
        s[0] += wa.x * c[t]; s[1] += wa.y * c[t]; s[2] += wa.z * c[t]; s[3] += wa.w * c[t];
        s[4] += wb.x * c[t]; s[5] += wb.y * c[t]; s[6] += wb.z * c[t]; s[7] += wb.w * c[t];
    }
#pragma unroll
    for (int off = 1; off < 64; off <<= 1)
#pragma unroll
        for (int j = 0; j < 8; ++j)
            s[j] += __shfl_xor(s[j], off, 64);
    if (lane == 0) {
        float* o = zwT + (long)Q * 8;
        *(float4*)o = make_float4(s[0], s[1], s[2], s[3]);
        *(float4*)(o + 4) = make_float4(s[4], s[5], s[6], s[7]);
    }
}

// ---------------- fuse_weights: v1=w_l1@i1 ; v2=CARAFE(zw)+c2 -> lw0 ----------------
__global__ __launch_bounds__(256) void fuse_weights_kernel(
    const float* __restrict__ input1, const float* __restrict__ zwT,
    const float* __restrict__ maskb, const float* __restrict__ bnp,  // 512.. c2
    const float* __restrict__ w_l1, const float* __restrict__ bn_l1,
    const float* __restrict__ bn_l2, const float* __restrict__ w_wl,
    const float* __restrict__ b_wl, float* __restrict__ lw0g)
{
    __shared__ float red[4][64][8];
    __shared__ float zws[3 * 34 * 8];
    __shared__ float ml[32 * 36];
    const int bx = blockIdx.x;              // 8 * 64
    const int n = bx >> 6;
    const int h = bx & 63;
    const int hq = h >> 1;
    const int p0 = h << 6;
    const int tid = threadIdx.x;

    for (int idx = tid; idx < 816; idx += 256) {
        int r = idx / 272, rem = idx - r * 272;
        int c = rem >> 3, j = rem & 7;
        int gr = hq - 1 + r, gc = c - 1;
        zws[(r * 34 + c) * 8 + j] =
            (gr >= 0 && gr < 32 && gc >= 0 && gc < 32)
                ? zwT[((long)n * 1024 + gr * 32 + gc) * 8 + j] : 0.f;
    }
    for (int idx = tid; idx < 1152; idx += 256)
        ml[idx] = maskb[((long)n * 1024 + hq * 32) * 36 + idx];

    const int pos = tid & 63;
    const int chunk = tid >> 6;
    const float* i1 = input1 + (long)n * 256 * 4096 + p0 + pos;
    {
        float s1[8] = {};
        for (int ci = chunk * 64; ci < chunk * 64 + 64; ++ci) {
            float x1 = i1[(long)ci * 4096];
#pragma unroll
            for (int j = 0; j < 8; ++j) s1[j] += w_l1[j * 256 + ci] * x1;
        }
#pragma unroll
        for (int j = 0; j < 8; ++j) red[chunk][pos][j] = s1[j];
    }
    __syncthreads();
    if (tid < 64) {
        float v[16];
#pragma unroll
        for (int j = 0; j < 8; ++j)
            v[j] = red[0][tid][j] + red[1][tid][j] + red[2][tid][j] + red[3][tid][j];
        const int wq = tid >> 1;
        const int q = ((h & 1) << 1) | (tid & 1);
        float m9[9];
#pragma unroll
        for (int k = 0; k < 9; ++k) m9[k] = ml[wq * 36 + k * 4 + q];
#pragma unroll
        for (int j = 0; j < 8; ++j) v[8 + j] = bnp[512 + j];
#pragma unroll
        for (int k = 0; k < 9; ++k) {
            int dh = k / 3 - 1, dw = k - (k / 3) * 3 - 1;
            const float* zp = zws + ((1 + dh) * 34 + wq + 1 + dw) * 8;
            float mk = m9[k];
#pragma unroll
            for (int j = 0; j < 8; ++j) v[8 + j] += mk * zp[j];
        }
        float z0 = b_wl[0], z1 = b_wl[1];
#pragma unroll
        for (int j = 0; j < 8; ++j) {
            float g = bn_l1[j], b = bn_l1[8 + j], m = bn_l1[16 + j], va = bn_l1[24 + j];
            float y = (v[j] - m) * (g * rsqrtf(va + EPS)) + b;
            float sv = y / (1.f + expf(-y));
            z0 += w_wl[j] * sv;
            z1 += w_wl[16 + j] * sv;
            g = bn_l2[j]; b = bn_l2[8 + j]; m = bn_l2[16 + j]; va = bn_l2[24 + j];
            y = (v[8 + j] - m) * (g * rsqrtf(va + EPS)) + b;
            sv = y / (1.f + expf(-y));
            z0 += w_wl[8 + j] * sv;
            z1 += w_wl[24 + j] * sv;
        }
        lw0g[(long)n * 4096 + p0 + tid] = 1.f / (1.f + expf(z1 - z0));
    }
}

// ---------------- border_zero ----------------
__global__ __launch_bounds__(256) void border_zero_kernel(u16* __restrict__ ftb)
{
    int gid = blockIdx.x * 256 + threadIdx.x;   // 8 * 260 * 32 uint4
    if (gid >= 8 * 260 * 32) return;
    int n = gid / (260 * 32);
    int rem = gid - n * (260 * 32);
    int r = rem >> 5;
    int i = rem & 31;
    int h, w;
    if (r < 66)       { h = 0;  w = r; }
    else if (r < 132) { h = 65; w = r - 66; }
    else { int j = r - 132; h = 1 + (j >> 1); w = (j & 1) * 65; }
    long prow = (long)h * 66 + w;
    uint4* dst = (uint4*)(ftb + (long)n * 4356 * 256 + prow * 256) + i;
    *dst = make_uint4(0, 0, 0, 0);
}

// ---------------- carafe_blend: u=CARAFE(z)+b_up ; blend ; transposed write ----------------
__global__ __launch_bounds__(256) void carafe_blend_kernel(
    const float* __restrict__ i1g, const u16* __restrict__ zbfT,
    const float* __restrict__ maskb, const float* __restrict__ lw0g,
    const float* __restrict__ bnp,          // 768.. b_up
    u16* __restrict__ dst)
{
    __shared__ __align__(16) u16 zbf[54 * 264];
    __shared__ float mlds[16 * 36];
    __shared__ float lw0s[32];
    __shared__ __align__(16) u16 lds2[32 * 264];
    const int n = blockIdx.y;
    const int h = blockIdx.x >> 1;
    const int w0 = (blockIdx.x & 1) << 5;
    const int hq = h >> 1;
    const int wq0 = w0 >> 1;
    const int tid = threadIdx.x;

    for (int idx = tid; idx < 54 * 32; idx += 256) {
        int px = idx >> 5, unit = idx & 31;
        int r = px / 18, c = px - r * 18;
        int gr = hq - 1 + r, gc = wq0 - 1 + c;
        uint4 v = make_uint4(0u, 0u, 0u, 0u);
        if (gr >= 0 && gr < 32 && gc >= 0 && gc < 32)
            v = *(const uint4*)(zbfT + ((long)n * 1024 + gr * 32 + gc) * 256 + unit * 8);
        *(uint4*)(zbf + px * 264 + unit * 8) = v;
    }
    for (int idx = tid; idx < 576; idx += 256)
        mlds[idx] = maskb[((long)n * 1024 + hq * 32 + wq0) * 36 + idx];
    if (tid < 32)
        lw0s[tid] = lw0g[(long)n * 4096 + (h << 6) + w0 + tid];
    __syncthreads();

    const int w = tid & 31;
    const int chunk = tid >> 5;
    const float* i1 = i1g + (long)n * 256 * 4096 + (h << 6) + w0 + w;
    {
        const float lw = lw0s[w], lw1 = 1.f - lw;
        const int wp = w0 + w;
        const int wqm = (wp >> 1) - wq0;
        const int q = ((h & 1) << 1) | (wp & 1);
        float m9[9];
#pragma unroll
        for (int k = 0; k < 9; ++k) m9[k] = mlds[wqm * 36 + k * 4 + q];
        for (int ci = chunk * 32; ci < chunk * 32 + 32; ci += 8) {
            float uu[8];
            {
                float4 ba = *(const float4*)(bnp + 768 + ci);
                float4 bb = *(const float4*)(bnp + 768 + ci + 4);
                uu[0] = ba.x; uu[1] = ba.y; uu[2] = ba.z; uu[3] = ba.w;
                uu[4] = bb.x; uu[5] = bb.y; uu[6] = bb.z; uu[7] = bb.w;
            }
#pragma unroll
            for (int k = 0; k < 9; ++k) {
                int dh = k / 3 - 1, dw = k - (k / 3) * 3 - 1;
                uint4 vz = *(const uint4*)(zbf + ((1 + dh) * 18 + wqm + 1 + dw) * 264 + ci);
                float mk = m9[k];
                uu[0] += mk * bf2f((u16)(vz.x & 0xffff));
                uu[1] += mk * bf2f((u16)(vz.x >> 16));
                uu[2] += mk * bf2f((u16)(vz.y & 0xffff));
                uu[3] += mk * bf2f((u16)(vz.y >> 16));
                uu[4] += mk * bf2f((u16)(vz.z & 0xffff));
                uu[5] += mk * bf2f((u16)(vz.z >> 16));
                uu[6] += mk * bf2f((u16)(vz.w & 0xffff));
                uu[7] += mk * bf2f((u16)(vz.w >> 16));
            }
            unsigned o0 = (unsigned)f2bf(i1[(long)ci * 4096] * lw + uu[0] * lw1)
                        | ((unsigned)f2bf(i1[(long)(ci + 1) * 4096] * lw + uu[1] * lw1) << 16);
            unsigned o1 = (unsigned)f2bf(i1[(long)(ci + 2) * 4096] * lw + uu[2] * lw1)
                        | ((unsigned)f2bf(i1[(long)(ci + 3) * 4096] * lw + uu[3] * lw1) << 16);
            unsigned o2 = (unsigned)f2bf(i1[(long)(ci + 4) * 4096] * lw + uu[4] * lw1)
                        | ((unsigned)f2bf(i1[(long)(ci + 5) * 4096] * lw + uu[5] * lw1) << 16);
            unsigned o3 = (unsigned)f2bf(i1[(long)(ci + 6) * 4096] * lw + uu[6] * lw1)
                        | ((unsigned)f2bf(i1[(long)(ci + 7) * 4096] * lw + uu[7] * lw1) << 16);
            *(uint4*)(lds2 + w * 264 + ci) = make_uint4(o0, o1, o2, o3);
        }
    }
    __syncthreads();
    {
        const int px = tid >> 3, qd = tid & 7;
        const int pg = (h << 6) + w0 + px;
        long prow = (long)((pg >> 6) + 1) * 66 + (pg & 63) + 1;
        u16* drow = dst + (long)n * 4356 * 256 + prow * 256;
        const u16* lrow = lds2 + px * 264;
#pragma unroll
        for (int j = 0; j < 16; ++j) {
            int off = j * 16 + qd * 2;
            *(unsigned*)(drow + off) = *(const unsigned*)(lrow + off);
        }
    }
}

// ---------------- K7: m97 GEMM — post-barrier 3-deep A staging, exact vmcnt ladder ----------------
// In-order retirement accounting (per phase s = kx*NT + t):
//   need: A(s) (issued s-3), B(kx) (issued 9 phases back).
//   newer-than-A(s): A(s+1),A(s+2) = 4; + B(kx+1) (t==1,2, kx<NKX-1) -> 8.
//   tail: s==S-2 -> 2, s==S-1 -> 0. Over-draining old B (t>=3) is harmless.
// WAR safety: writes happen post-barrier; every wave's previous-phase ds_reads
// complete before it passes the barrier, so A(s+3) -> buffer (s-1)%4 is safe.
template<int KCC, int NT, bool PADDED>
__global__ __launch_bounds__(256, 2) void gemm_m97_kernel(
    const u16* __restrict__ A,      // [NT][256][KCC] bf16
    const u16* __restrict__ B,      // per image [rows][KCC] bf16
    const float* __restrict__ scale, const float* __restrict__ shift,
    float* __restrict__ C, long strideB, long strideC, int silu)
{
    constexpr int RROWS = PADDED ? 264 : 128;
    constexpr int BUNITS = RROWS * 4;
    constexpr int NKX = KCC / 32;
    constexpr int S = NKX * NT;
    __shared__ __align__(16) u16 lsA[4][128 * 32];
    __shared__ __align__(16) u16 lsB[2][RROWS * 32];
    const int n = blockIdx.z;
    const u16* Bn = B + (long)n * strideB;
    float* Cn = C + (long)n * strideC;
    const int tid = threadIdx.x;
    const int lane = tid & 63;
    const int wid = tid >> 6;
    const int mw = wid >> 1, nw = wid & 1;
    const int lr = lane & 15, lk = lane >> 4;
    const int rowBase = blockIdx.y * 128;
    const int colBase = blockIdx.x * 128;
    const int g0 = PADDED ? (colBase >> 6) * 66 : colBase;

    // prologue: B(0), then A(0..2)
    STAGE_B(lsB[0], 0);
    STAGE_A(lsA[0], 0, 0);
    { constexpr int s1 = 1, kx1 = s1 / NT, t1 = s1 - kx1 * NT; STAGE_A(lsA[1], t1, kx1); }
    { constexpr int s2 = 2, kx2 = s2 / NT, t2 = s2 - kx2 * NT; STAGE_A(lsA[2], t2, kx2); }

    const int aswz = (lk ^ ((lr >> 1) & 3)) << 3;
    int aoff[4];
#pragma unroll
    for (int mf = 0; mf < 4; ++mf)
        aoff[mf] = (mw * 64 + mf * 16 + lr) * 32 + aswz;

    f32x4 acc[4][4] = {};
    for (int kx = 0; kx < NKX; ++kx) {
        const u16* lb = lsB[kx & 1];
#pragma unroll
        for (int t = 0; t < NT; ++t) {
            const int s = kx * NT + t;
            if (kx == NKX - 1) {
                if (t == NT - 1) { VMCNT(0); }
                else if (t == NT - 2) { VMCNT(2); }
                else { VMCNT(4); }
            } else if (t == 1 || t == 2) { VMCNT(8); }
            else { VMCNT(4); }
            __builtin_amdgcn_s_barrier();
            asm volatile("" ::: "memory");
            // post-barrier issues
            if (s + 3 < S) {
                const int s3 = s + 3;
                const int kx3 = s3 / NT;
                const int t3 = s3 - kx3 * NT;
                STAGE_A(lsA[s3 & 3], t3, kx3);
            }
            if (t == 0 && kx + 1 < NKX) STAGE_B(lsB[(kx + 1) & 1], kx + 1);

            const u16* la = lsA[s & 3];
            bf16x8 af[4], bfr[4];
#pragma unroll
            for (int mf = 0; mf < 4; ++mf)
                af[mf] = *(const bf16x8*)(la + aoff[mf]);
            int rb;
            if (PADDED) {
                int dh = t / 3 - 1, dw = t - (t / 3) * 3 - 1;
                rb = (nw + dh + 1) * 66 + dw + 1 + lr;
            } else {
                rb = nw * 64 + lr;
            }
            const int bswz = (lk ^ ((rb >> 1) & 3)) << 3;
#pragma unroll
            for (int nf = 0; nf < 4; ++nf)
                bfr[nf] = *(const bf16x8*)(lb + (rb + nf * 16) * 32 + bswz);
#pragma unroll
            for (int mf = 0; mf < 4; ++mf)
#pragma unroll
                for (int nf = 0; nf < 4; ++nf)
                    acc[mf][nf] = __builtin_amdgcn_mfma_f32_16x16x32_bf16(
                        af[mf], bfr[nf], acc[mf][nf], 0, 0, 0);
        }
    }

#pragma unroll
    for (int mf = 0; mf < 4; ++mf) {
#pragma unroll
        for (int reg = 0; reg < 4; ++reg) {
            int co = rowBase + mw * 64 + mf * 16 + lk * 4 + reg;
            float sc = scale[co], sh = shift[co];
#pragma unroll
            for (int nf = 0; nf < 4; ++nf) {
                int col = colBase + nw * 64 + nf * 16 + lr;
                float y = acc[mf][nf][reg] * sc + sh;
                if (silu) y = y / (1.f + expf(-y));
                Cn[(long)co * 4096 + col] = y;
            }
        }
    }
}

// ---------------- prep kernels ----------------
__global__ __launch_bounds__(256) void prep_w_kernel(
    const float* __restrict__ w_conv, const float* __restrict__ w_up,
    const float* __restrict__ w_enc, const float* __restrict__ w_down,
    u16* __restrict__ wT, u16* __restrict__ wupT, u16* __restrict__ wencT,
    u16* __restrict__ wdT)
{
    int gid = blockIdx.x * 256 + threadIdx.x;
    if (gid < 589824) {             // wT[t][co][ci] = w_conv[co][ci][t]
        int t = gid >> 16;
        int co = (gid >> 8) & 255;
        int ci = gid & 255;
        wT[gid] = f2bf(w_conv[(co * 256 + ci) * 9 + t]);
    }
    if (gid < 131072) wupT[gid] = f2bf(w_up[gid]);
    if (gid < 73728) {              // wencT[t][co<64][ci] (zeros co>=36)
        int t = gid >> 13;
        int co = (gid >> 7) & 63;
        int ci = gid & 127;
        wencT[gid] = (co < 36) ? f2bf(w_enc[(co * 128 + ci) * 9 + t]) : (u16)0;
    }
    if (gid < 65536) wdT[gid] = f2bf(w_down[gid]);
}

__global__ void prep_bn_kernel(const float* __restrict__ bn_conv,
                               const float* __restrict__ b_up,
                               const float* __restrict__ w_l2,
                               float* __restrict__ bnp, float* __restrict__ wl2T)
{
    int i = threadIdx.x;            // 256
    float g = bn_conv[i], b = bn_conv[256 + i], m = bn_conv[512 + i], v = bn_conv[768 + i];
    float sc = g * rsqrtf(v + EPS);
    bnp[i] = sc;
    bnp[256 + i] = b - m * sc;
    bnp[768 + i] = b_up[i];
    if (i < 8) {                    // c2[j] = w_l2[j] . b_up
        float s = 0.f;
        for (int co = 0; co < 256; ++co) s += w_l2[i * 256 + co] * b_up[co];
        bnp[512 + i] = s;
    }
#pragma unroll
    for (int j = 0; j < 8; ++j)     // wl2T[co][j]
        wl2T[i * 8 + j] = w_l2[j * 256 + i];
}

extern "C" void kernel_launch(void* const* d_in, const int* in_sizes, int n_in,
                              void* d_out, int out_size, void* d_ws, size_t ws_size,
                              hipStream_t stream)
{
    const float* input1 = (const float*)d_in[0];
    const float* input2 = (const float*)d_in[1];
    const float* w_down = (const float*)d_in[2];
    const float* b_down = (const float*)d_in[3];
    const float* w_enc  = (const float*)d_in[4];
    const float* b_enc  = (const float*)d_in[5];
    const float* w_up   = (const float*)d_in[6];
    const float* b_up   = (const float*)d_in[7];
    const float* w_l1   = (const float*)d_in[8];
    const float* bn_l1  = (const float*)d_in[9];
    const float* w_l2   = (const float*)d_in[10];
    const float* bn_l2  = (const float*)d_in[11];
    const float* w_wl   = (const float*)d_in[12];
    const float* b_wl   = (const float*)d_in[13];
    const float* w_conv = (const float*)d_in[14];
    const float* bn_conv= (const float*)d_in[15];
    float* out = (float*)d_out;

    // workspace layout (float units). ~38 MB total.
    float* ws     = (float*)d_ws;
    float* ktTf   = ws;                      //   591,872 f : ktT bf16 [n][1156][128]
    float* wencTf = ktTf + 591872;           //    36,864 f
    float* kt2    = wencTf + 36864;          //   294,912 f
    float* maskb  = kt2 + 294912;            //   294,912 f
    float* in2Tf  = maskb + 294912;          // 2,097,152 f : in2T bf16 [n][1024][512]
    float* zbfTf  = in2Tf + 2097152;         // 1,048,576 f : zbfT bf16 [n][1024][256]
    float* zwT    = zbfTf + 1048576;         //    65,536 f : [n][1024][8] fp32
    float* lw0g   = zwT + 65536;             //    32,768 f : [n][4096]
    float* ftbf   = lw0g + 32768;            // 4,460,544 f : fusedT bf16 [n][4356][256]
    float* wTf    = ftbf + 4460544;          //   294,912 f
    float* wupTf  = wTf + 294912;            //    65,536 f
    float* wdTf   = wupTf + 65536;           //    32,768 f
    float* wl2T   = wdTf + 32768;            //     2,048 f
    float* bnp    = wl2T + 2048;             //     1,024 f
    u16* ktT      = (u16*)ktTf;
    u16* wencT    = (u16*)wencTf;
    u16* in2T     = (u16*)in2Tf;
    u16* zbfT     = (u16*)zbfTf;
    u16* ftb      = (u16*)ftbf;
    u16* wT       = (u16*)wTf;
    u16* wupT     = (u16*)wupTf;
    u16* wdT      = (u16*)wdTf;

    // prep (independent)
    prep_w_kernel<<<dim3(2304), 256, 0, stream>>>(w_conv, w_up, w_enc, w_down,
                                                  wT, wupT, wencT, wdT);
    prep_bn_kernel<<<dim3(1), 256, 0, stream>>>(bn_conv, b_up, w_l2, bnp, wl2T);
    border_zero_kernel<<<dim3(260), 256, 0, stream>>>(ftb);
    hipMemsetAsync(ktT, 0, 8L * 1156 * 128 * 2, stream);

    // in2T first (feeds down_mfma and zgemm)
    in2t_kernel<<<dim3(32, 8), 256, 0, stream>>>(input2, in2T);

    // mask pipeline
    down_mfma_kernel<<<dim3(8, 1, 8), 256, 0, stream>>>(wdT, in2T, b_down, ktT);
    enc_mfma_kernel<<<dim3(64, 8), 64, 0, stream>>>(wencT, ktT, b_enc, kt2);
    mask_softmax_kernel<<<dim3(128), 256, 0, stream>>>(kt2, maskb);

    // z pipeline
    zgemm_kernel<<<dim3(8, 2, 8), 256, 0, stream>>>(wupT, in2T, zbfT);
    zw_kernel<<<dim3(2048), 256, 0, stream>>>(zbfT, wl2T, zwT);

    // level weights -> lw0 (reads i1 once)
    fuse_weights_kernel<<<dim3(512), 256, 0, stream>>>(
        input1, zwT, maskb, bnp, w_l1, bn_l1, bn_l2, w_wl, b_wl, lw0g);

    // CARAFE + blend -> fusedT
    carafe_blend_kernel<<<dim3(128, 8), 256, 0, stream>>>(
        input1, zbfT, maskb, lw0g, bnp, ftb);

    // K7: final conv + BN + SiLU
    gemm_m97_kernel<256, 9, true><<<dim3(32, 2, 8), 256, 0, stream>>>(
        wT, ftb, bnp, bnp + 256, out, 4356L * 256, 256L * 4096, 1);
}

// Round 17
// 164.783 us; speedup vs baseline: 1.0645x; 1.0645x over previous
//
#include <hip/hip_runtime.h>
#include <math.h>

// ASFF_2: N=8, C1=256, C2=512, H=64, W=64, low-res 32x32.
// CARAFE-commutation: u = CARAFE(z)+b_up with z = w_up@in2 (low-res GEMM);
// v2 = CARAFE(zw)+c2 with zw = w_l2@z, c2 = w_l2@b_up.
//  in2t: input2 -> in2T bf16 [n][1024][512]  (64-px tiles, 256B-coalesced)
//  lowres_gemm (merged): y<2 -> zbfT = bf16(w_up @ in2T); y==2 -> ktT =
//      bf16T(w_down @ in2T + b_down) padded 34x34   (m97+T4, 192 blocks)
//  enc_mfma -> kt2 ; softmax -> maskb
//  zw: zwT[n][1024][8] = w_l2 @ z
//  fuse_weights: v1 = w_l1@i1, v2 = CARAFE(zw)+c2 -> lw0[n][4096]
//  carafe_blend: u=CARAFE(z)+b_up, blend with i1 -> fusedT bf16 [66x66][256]
//  K7: m97 GEMM, post-barrier 2-phase-deep A staging (round-15 proven; the
//      3-deep ladder REGRESSED 54.7->60 and was reverted).

#define EPS 1e-5f
typedef unsigned short u16;
typedef __attribute__((ext_vector_type(8))) __bf16 bf16x8;
typedef __attribute__((ext_vector_type(4))) float f32x4;

#define VMCNT(N) asm volatile("s_waitcnt vmcnt(" #N ")" ::: "memory")

__device__ inline u16 f2bf(float x) {
    union { float f; unsigned u; } v; v.f = x;
    unsigned r = v.u + 0x7FFF + ((v.u >> 16) & 1);
    return (u16)(r >> 16);
}
__device__ inline float bf2f(u16 x) {
    union { unsigned u; float f; } v; v.u = (unsigned)x << 16; return v.f;
}

// ---------------- in2t: transpose-cast input2 [512][1024] -> in2T bf16 [q][512] ----------------
// 64-px tile: each 64-lane wave reads one ci row's 64 consecutive floats (256B).
__global__ __launch_bounds__(256) void in2t_kernel(
    const float* __restrict__ src0, u16* __restrict__ dst)
{
    constexpr int CP = 516;
    __shared__ u16 lds[64 * CP];
    const int n = blockIdx.y;
    const int p0 = blockIdx.x * 64;
    const int tid = threadIdx.x;
    {
        const int px = tid & 63;
        const float* src = src0 + (long)n * 512 * 1024 + p0 + px;
        for (int ci = tid >> 6; ci < 512; ci += 4)
            lds[px * CP + ci] = f2bf(src[(long)ci * 1024]);
    }
    __syncthreads();
    const int px = tid >> 2;
    const int qd = tid & 3;
    u16* drow = dst + ((long)n * 1024 + p0 + px) * 512;
    const u16* lrow = lds + px * CP;
#pragma unroll
    for (int j = 0; j < 16; ++j) {
        int off = j * 32 + qd * 8;
        *(uint4*)(drow + off) = *(const uint4*)(lrow + off);
    }
}

// ---------------- staging macros ----------------
#define STAGE_A(dstp, t, kx)                                                         \
    {                                                                                \
        const u16* Abase = A + ((long)(t) * 256 + rowBase) * KCC + (kx) * 32;        \
        _Pragma("unroll")                                                            \
        for (int ii = 0; ii < 2; ++ii) {                                             \
            int f = ii * 256 + tid;                                                  \
            int r = f >> 2, uu = f & 3;                                              \
            __builtin_amdgcn_global_load_lds(                                        \
                (const __attribute__((address_space(1))) void*)                      \
                    (Abase + (long)r * KCC + ((uu ^ ((r >> 1) & 3)) << 3)),          \
                (__attribute__((address_space(3))) void*)((dstp) + f * 8),           \
                16, 0, 0);                                                           \
        }                                                                            \
    }

#define STAGE_B(dstp, kx)                                                            \
    {                                                                                \
        const u16* Bbase = Bn + (long)g0 * KCC + (kx) * 32;                          \
        for (int f = tid; f < BUNITS; f += 256) {                                    \
            int r = f >> 2, uu = f & 3;                                              \
            __builtin_amdgcn_global_load_lds(                                        \
                (const __attribute__((address_space(1))) void*)                      \
                    (Bbase + (long)r * KCC + ((uu ^ ((r >> 1) & 3)) << 3)),          \
                (__attribute__((address_space(3))) void*)((dstp) + f * 8),           \
                16, 0, 0);                                                           \
        }                                                                            \
    }

// ---------------- lowres_gemm (merged zgemm + down_mfma) ----------------
// grid (8, 3, 8): y<2 -> A=wupT rows y*128 -> zbfT ; y==2 -> A=wdT -> ktT+bias.
// m97+T4: KCC=512, 16 phases, post-barrier 2-phase lead, triple-buffered, VMCNT(4).
__global__ __launch_bounds__(256, 2) void lowres_gemm_kernel(
    const u16* __restrict__ Aup,    // wupT [256][512]
    const u16* __restrict__ Adn,    // wdT  [128][512]
    const u16* __restrict__ B,      // in2T [n][1024][512]
    const float* __restrict__ bias, // b_down
    u16* __restrict__ Z,            // zbfT [n][1024][256]
    u16* __restrict__ ktT)          // [n][1156][128] padded
{
    constexpr int KCC = 512;
    constexpr int BUNITS = 512;
    __shared__ __align__(16) u16 lsA[3][128 * 32];
    __shared__ __align__(16) u16 lsB[3][128 * 32];
    const int n = blockIdx.z;
    const u16* Bn = B + (long)n * 1024 * 512;
    const int tid = threadIdx.x;
    const int lane = tid & 63;
    const int wid = tid >> 6;
    const int mw = wid >> 1, nw = wid & 1;
    const int lr = lane & 15, lk = lane >> 4;
    const int ybr = blockIdx.y;
    const u16* A = (ybr < 2) ? Aup : Adn;
    const int rowBase = (ybr < 2) ? ybr * 128 : 0;
    const int colBase = blockIdx.x * 128;
    const int g0 = colBase;

    STAGE_A(lsA[0], 0, 0); STAGE_B(lsB[0], 0);
    STAGE_A(lsA[1], 0, 1); STAGE_B(lsB[1], 1);

    const int aswz = (lk ^ ((lr >> 1) & 3)) << 3;
    int aoff[4];
#pragma unroll
    for (int mf = 0; mf < 4; ++mf)
        aoff[mf] = (mw * 64 + mf * 16 + lr) * 32 + aswz;

    f32x4 acc[4][4] = {};
    for (int kx = 0; kx < 16; ++kx) {
        if (kx == 15) { VMCNT(0); } else { VMCNT(4); }
        __builtin_amdgcn_s_barrier();
        asm volatile("" ::: "memory");
        if (kx + 2 < 16) {
            STAGE_A(lsA[(kx + 2) % 3], 0, kx + 2);
            STAGE_B(lsB[(kx + 2) % 3], kx + 2);
        }
        const u16* la = lsA[kx % 3];
        const u16* lb = lsB[kx % 3];
        bf16x8 af[4], bfr[4];
#pragma unroll
        for (int mf = 0; mf < 4; ++mf)
            af[mf] = *(const bf16x8*)(la + aoff[mf]);
        const int rb = nw * 64 + lr;
        const int bswz = (lk ^ ((rb >> 1) & 3)) << 3;
#pragma unroll
        for (int nf = 0; nf < 4; ++nf)
            bfr[nf] = *(const bf16x8*)(lb + (rb + nf * 16) * 32 + bswz);
#pragma unroll
        for (int mf = 0; mf < 4; ++mf)
#pragma unroll
            for (int nf = 0; nf < 4; ++nf)
                acc[mf][nf] = __builtin_amdgcn_mfma_f32_16x16x32_bf16(
                    af[mf], bfr[nf], acc[mf][nf], 0, 0, 0);
    }

    if (ybr < 2) {
        u16* Zn = Z + (long)n * 1024 * 256;
#pragma unroll
        for (int mf = 0; mf < 4; ++mf) {
            const int co0 = rowBase + mw * 64 + mf * 16 + lk * 4;
#pragma unroll
            for (int nf = 0; nf < 4; ++nf) {
                const int col = colBase + nw * 64 + nf * 16 + lr;
                unsigned lo = (unsigned)f2bf(acc[mf][nf][0]) |
                              ((unsigned)f2bf(acc[mf][nf][1]) << 16);
                unsigned hi = (unsigned)f2bf(acc[mf][nf][2]) |
                              ((unsigned)f2bf(acc[mf][nf][3]) << 16);
                *(uint2*)(Zn + (long)col * 256 + co0) = make_uint2(lo, hi);
            }
        }
    } else {
        u16* Kn = ktT + (long)n * 1156 * 128;
#pragma unroll
        for (int mf = 0; mf < 4; ++mf) {
            const int co0 = mw * 64 + mf * 16 + lk * 4;     // 0..124
            float b0 = bias[co0], b1 = bias[co0 + 1], b2 = bias[co0 + 2], b3 = bias[co0 + 3];
#pragma unroll
            for (int nf = 0; nf < 4; ++nf) {
                const int col = colBase + nw * 64 + nf * 16 + lr;   // 0..1023
                const int pr = ((col >> 5) + 1) * 34 + (col & 31) + 1;
                unsigned lo = (unsigned)f2bf(acc[mf][nf][0] + b0) |
                              ((unsigned)f2bf(acc[mf][nf][1] + b1) << 16);
                unsigned hi = (unsigned)f2bf(acc[mf][nf][2] + b2) |
                              ((unsigned)f2bf(acc[mf][nf][3] + b3) << 16);
                *(uint2*)(Kn + (long)pr * 128 + co0) = make_uint2(lo, hi);
            }
        }
    }
}

// ---------------- enc_mfma: encoder conv as 9-tap shifted MFMA GEMM ----------------
__global__ __launch_bounds__(64) void enc_mfma_kernel(
    const u16* __restrict__ A, const u16* __restrict__ B,
    const float* __restrict__ bias, float* __restrict__ C)
{
    const int n = blockIdx.y;
    const int lane = threadIdx.x;
    const int lr = lane & 15, lk = lane >> 4;
    const int p = blockIdx.x * 16 + lr;
    const int pr = ((p >> 5) + 1) * 34 + (p & 31) + 1;
    const u16* Bn = B + (long)n * 1156 * 128;
    const int bOff = pr * 128 + lk * 8;
    f32x4 acc[3] = {};
    for (int t = 0; t < 9; ++t) {
        const u16* At = A + t * 8192;
        const int btap = ((t / 3 - 1) * 34 + (t % 3 - 1)) * 128;
#pragma unroll
        for (int k0 = 0; k0 < 128; k0 += 32) {
            bf16x8 bf = *(const bf16x8*)(Bn + bOff + btap + k0);
#pragma unroll
            for (int mf = 0; mf < 3; ++mf) {
                bf16x8 af = *(const bf16x8*)(At + (mf * 16 + lr) * 128 + lk * 8 + k0);
                acc[mf] = __builtin_amdgcn_mfma_f32_16x16x32_bf16(af, bf, acc[mf], 0, 0, 0);
            }
        }
    }
    float* Cn = C + (long)n * 36 * 1024;
#pragma unroll
    for (int mf = 0; mf < 3; ++mf)
#pragma unroll
        for (int reg = 0; reg < 4; ++reg) {
            int co = mf * 16 + lk * 4 + reg;
            if (co < 36)
                Cn[(long)co * 1024 + p] = acc[mf][reg] + bias[co];
        }
}

// ---------------- softmax over k=9 ----------------
__global__ __launch_bounds__(256) void mask_softmax_kernel(
    const float* __restrict__ kt2, float* __restrict__ mask)
{
    int gid = blockIdx.x * 256 + threadIdx.x;   // N*1024*4
    int q = gid & 3;
    int p = (gid >> 2) & 1023;
    int n = gid >> 12;
    float s[9];
    float mx = -1e30f;
#pragma unroll
    for (int k = 0; k < 9; ++k) {
        s[k] = kt2[(long)(n * 36 + k * 4 + q) * 1024 + p];
        mx = fmaxf(mx, s[k]);
    }
    float sum = 0.f;
#pragma unroll
    for (int k = 0; k < 9; ++k) { s[k] = expf(s[k] - mx); sum += s[k]; }
    float inv = 1.f / sum;
    float* mp = mask + (long)(n * 1024 + p) * 36 + q;
#pragma unroll
    for (int k = 0; k < 9; ++k) mp[k * 4] = s[k] * inv;
}

// ---------------- zw: one wave per low-res pixel, butterfly reduce ----------------
__global__ __launch_bounds__(256) void zw_kernel(
    const u16* __restrict__ zbfT, const float* __restrict__ wl2T,
    float* __restrict__ zwT)
{
    const int Q = (blockIdx.x * 256 + threadIdx.x) >> 6;   // 0..8191
    const int lane = threadIdx.x & 63;
    const int ci0 = lane * 4;
    uint2 v = *(const uint2*)(zbfT + (long)Q * 256 + ci0);
    float c[4] = { bf2f((u16)(v.x & 0xffff)), bf2f((u16)(v.x >> 16)),
                   bf2f((u16)(v.y & 0xffff)), bf2f((u16)(v.y >> 16)) };
    float s[8] = {};
#pragma unroll
    for (int t = 0; t < 4; ++t) {
        const float* wr = wl2T + (ci0 + t) * 8;
        float4 wa = *(const float4*)wr;
        float4 wb = *(const float4*)(wr + 4);
        s[0] += wa.x * c[t]; s[1] += wa.y * c[t]; s[2] += wa.z * c[t]; s[3] += wa.w * c[t];
        s[4] += wb.x * c[t]; s[5] += wb.y * c[t]; s[6] += wb.z * c[t]; s[7] += wb.w * c[t];
    }
#pragma unroll
    for (int off = 1; off < 64; off <<= 1)
#pragma unroll
        for (int j = 0; j < 8; ++j)
            s[j] += __shfl_xor(s[j], off, 64);
    if (lane == 0) {
        float* o = zwT + (long)Q * 8;
        *(float4*)o = make_float4(s[0], s[1], s[2], s[3]);
        *(float4*)(o + 4) = make_float4(s[4], s[5], s[6], s[7]);
    }
}

// ---------------- fuse_weights: v1=w_l1@i1 ; v2=CARAFE(zw)+c2 -> lw0 ----------------
__global__ __launch_bounds__(256) void fuse_weights_kernel(
    const float* __restrict__ input1, const float* __restrict__ zwT,
    const float* __restrict__ maskb, const float* __restrict__ bnp,  // 512.. c2
    const float* __restrict__ w_l1, const float* __restrict__ bn_l1,
    const float* __restrict__ bn_l2, const float* __restrict__ w_wl,
    const float* __restrict__ b_wl, float* __restrict__ lw0g)
{
    __shared__ float red[4][64][8];
    __shared__ float zws[3 * 34 * 8];
    __shared__ float ml[32 * 36];
    const int bx = blockIdx.x;              // 8 * 64
    const int n = bx >> 6;
    const int h = bx & 63;
    const int hq = h >> 1;
    const int p0 = h << 6;
    const int tid = threadIdx.x;

    for (int idx = tid; idx < 816; idx += 256) {
        int r = idx / 272, rem = idx - r * 272;
        int c = rem >> 3, j = rem & 7;
        int gr = hq - 1 + r, gc = c - 1;
        zws[(r * 34 + c) * 8 + j] =
            (gr >= 0 && gr < 32 && gc >= 0 && gc < 32)
                ? zwT[((long)n * 1024 + gr * 32 + gc) * 8 + j] : 0.f;
    }
    for (int idx = tid; idx < 1152; idx += 256)
        ml[idx] = maskb[((long)n * 1024 + hq * 32) * 36 + idx];

    const int pos = tid & 63;
    const int chunk = tid >> 6;
    const float* i1 = input1 + (long)n * 256 * 4096 + p0 + pos;
    {
        float s1[8] = {};
        for (int ci = chunk * 64; ci < chunk * 64 + 64; ++ci) {
            float x1 = i1[(long)ci * 4096];
#pragma unroll
            for (int j = 0; j < 8; ++j) s1[j] += w_l1[j * 256 + ci] * x1;
        }
#pragma unroll
        for (int j = 0; j < 8; ++j) red[chunk][pos][j] = s1[j];
    }
    __syncthreads();
    if (tid < 64) {
        float v[16];
#pragma unroll
        for (int j = 0; j < 8; ++j)
            v[j] = red[0][tid][j] + red[1][tid][j] + red[2][tid][j] + red[3][tid][j];
        const int wq = tid >> 1;
        const int q = ((h & 1) << 1) | (tid & 1);
        float m9[9];
#pragma unroll
        for (int k = 0; k < 9; ++k) m9[k] = ml[wq * 36 + k * 4 + q];
#pragma unroll
        for (int j = 0; j < 8; ++j) v[8 + j] = bnp[512 + j];
#pragma unroll
        for (int k = 0; k < 9; ++k) {
            int dh = k / 3 - 1, dw = k - (k / 3) * 3 - 1;
            const float* zp = zws + ((1 + dh) * 34 + wq + 1 + dw) * 8;
            float mk = m9[k];
#pragma unroll
            for (int j = 0; j < 8; ++j) v[8 + j] += mk * zp[j];
        }
        float z0 = b_wl[0], z1 = b_wl[1];
#pragma unroll
        for (int j = 0; j < 8; ++j) {
            float g = bn_l1[j], b = bn_l1[8 + j], m = bn_l1[16 + j], va = bn_l1[24 + j];
            float y = (v[j] - m) * (g * rsqrtf(va + EPS)) + b;
            float sv = y / (1.f + expf(-y));
            z0 += w_wl[j] * sv;
            z1 += w_wl[16 + j] * sv;
            g = bn_l2[j]; b = bn_l2[8 + j]; m = bn_l2[16 + j]; va = bn_l2[24 + j];
            y = (v[8 + j] - m) * (g * rsqrtf(va + EPS)) + b;
            sv = y / (1.f + expf(-y));
            z0 += w_wl[8 + j] * sv;
            z1 += w_wl[24 + j] * sv;
        }
        lw0g[(long)n * 4096 + p0 + tid] = 1.f / (1.f + expf(z1 - z0));
    }
}

// ---------------- border_zero ----------------
__global__ __launch_bounds__(256) void border_zero_kernel(u16* __restrict__ ftb)
{
    int gid = blockIdx.x * 256 + threadIdx.x;   // 8 * 260 * 32 uint4
    if (gid >= 8 * 260 * 32) return;
    int n = gid / (260 * 32);
    int rem = gid - n * (260 * 32);
    int r = rem >> 5;
    int i = rem & 31;
    int h, w;
    if (r < 66)       { h = 0;  w = r; }
    else if (r < 132) { h = 65; w = r - 66; }
    else { int j = r - 132; h = 1 + (j >> 1); w = (j & 1) * 65; }
    long prow = (long)h * 66 + w;
    uint4* dst = (uint4*)(ftb + (long)n * 4356 * 256 + prow * 256) + i;
    *dst = make_uint4(0, 0, 0, 0);
}

// ---------------- carafe_blend: u=CARAFE(z)+b_up ; blend ; transposed write ----------------
__global__ __launch_bounds__(256) void carafe_blend_kernel(
    const float* __restrict__ i1g, const u16* __restrict__ zbfT,
    const float* __restrict__ maskb, const float* __restrict__ lw0g,
    const float* __restrict__ bnp,          // 768.. b_up
    u16* __restrict__ dst)
{
    __shared__ __align__(16) u16 zbf[54 * 264];
    __shared__ float mlds[16 * 36];
    __shared__ float lw0s[32];
    __shared__ __align__(16) u16 lds2[32 * 264];
    const int n = blockIdx.y;
    const int h = blockIdx.x >> 1;
    const int w0 = (blockIdx.x & 1) << 5;
    const int hq = h >> 1;
    const int wq0 = w0 >> 1;
    const int tid = threadIdx.x;

    for (int idx = tid; idx < 54 * 32; idx += 256) {
        int px = idx >> 5, unit = idx & 31;
        int r = px / 18, c = px - r * 18;
        int gr = hq - 1 + r, gc = wq0 - 1 + c;
        uint4 v = make_uint4(0u, 0u, 0u, 0u);
        if (gr >= 0 && gr < 32 && gc >= 0 && gc < 32)
            v = *(const uint4*)(zbfT + ((long)n * 1024 + gr * 32 + gc) * 256 + unit * 8);
        *(uint4*)(zbf + px * 264 + unit * 8) = v;
    }
    for (int idx = tid; idx < 576; idx += 256)
        mlds[idx] = maskb[((long)n * 1024 + hq * 32 + wq0) * 36 + idx];
    if (tid < 32)
        lw0s[tid] = lw0g[(long)n * 4096 + (h << 6) + w0 + tid];
    __syncthreads();

    const int w = tid & 31;
    const int chunk = tid >> 5;
    const float* i1 = i1g + (long)n * 256 * 4096 + (h << 6) + w0 + w;
    {
        const float lw = lw0s[w], lw1 = 1.f - lw;
        const int wp = w0 + w;
        const int wqm = (wp >> 1) - wq0;
        const int q = ((h & 1) << 1) | (wp & 1);
        float m9[9];
#pragma unroll
        for (int k = 0; k < 9; ++k) m9[k] = mlds[wqm * 36 + k * 4 + q];
        for (int ci = chunk * 32; ci < chunk * 32 + 32; ci += 8) {
            float uu[8];
            {
                float4 ba = *(const float4*)(bnp + 768 + ci);
                float4 bb = *(const float4*)(bnp + 768 + ci + 4);
                uu[0] = ba.x; uu[1] = ba.y; uu[2] = ba.z; uu[3] = ba.w;
                uu[4] = bb.x; uu[5] = bb.y; uu[6] = bb.z; uu[7] = bb.w;
            }
#pragma unroll
            for (int k = 0; k < 9; ++k) {
                int dh = k / 3 - 1, dw = k - (k / 3) * 3 - 1;
                uint4 vz = *(const uint4*)(zbf + ((1 + dh) * 18 + wqm + 1 + dw) * 264 + ci);
                float mk = m9[k];
                uu[0] += mk * bf2f((u16)(vz.x & 0xffff));
                uu[1] += mk * bf2f((u16)(vz.x >> 16));
                uu[2] += mk * bf2f((u16)(vz.y & 0xffff));
                uu[3] += mk * bf2f((u16)(vz.y >> 16));
                uu[4] += mk * bf2f((u16)(vz.z & 0xffff));
                uu[5] += mk * bf2f((u16)(vz.z >> 16));
                uu[6] += mk * bf2f((u16)(vz.w & 0xffff));
                uu[7] += mk * bf2f((u16)(vz.w >> 16));
            }
            unsigned o0 = (unsigned)f2bf(i1[(long)ci * 4096] * lw + uu[0] * lw1)
                        | ((unsigned)f2bf(i1[(long)(ci + 1) * 4096] * lw + uu[1] * lw1) << 16);
            unsigned o1 = (unsigned)f2bf(i1[(long)(ci + 2) * 4096] * lw + uu[2] * lw1)
                        | ((unsigned)f2bf(i1[(long)(ci + 3) * 4096] * lw + uu[3] * lw1) << 16);
            unsigned o2 = (unsigned)f2bf(i1[(long)(ci + 4) * 4096] * lw + uu[4] * lw1)
                        | ((unsigned)f2bf(i1[(long)(ci + 5) * 4096] * lw + uu[5] * lw1) << 16);
            unsigned o3 = (unsigned)f2bf(i1[(long)(ci + 6) * 4096] * lw + uu[6] * lw1)
                        | ((unsigned)f2bf(i1[(long)(ci + 7) * 4096] * lw + uu[7] * lw1) << 16);
            *(uint4*)(lds2 + w * 264 + ci) = make_uint4(o0, o1, o2, o3);
        }
    }
    __syncthreads();
    {
        const int px = tid >> 3, qd = tid & 7;
        const int pg = (h << 6) + w0 + px;
        long prow = (long)((pg >> 6) + 1) * 66 + (pg & 63) + 1;
        u16* drow = dst + (long)n * 4356 * 256 + prow * 256;
        const u16* lrow = lds2 + px * 264;
#pragma unroll
        for (int j = 0; j < 16; ++j) {
            int off = j * 16 + qd * 2;
            *(unsigned*)(drow + off) = *(const unsigned*)(lrow + off);
        }
    }
}

// ---------------- K7: m97 GEMM — post-barrier 2-deep A staging (round-15 proven) ----------------
template<int KCC, int NT, bool PADDED>
__global__ __launch_bounds__(256, 2) void gemm_m97_kernel(
    const u16* __restrict__ A,      // [NT][256][KCC] bf16
    const u16* __restrict__ B,      // per image [rows][KCC] bf16
    const float* __restrict__ scale, const float* __restrict__ shift,
    float* __restrict__ C, long strideB, long strideC, int silu)
{
    constexpr int RROWS = PADDED ? 264 : 128;
    constexpr int BUNITS = RROWS * 4;
    constexpr int NKX = KCC / 32;
    constexpr int S = NKX * NT;
    __shared__ __align__(16) u16 lsA[3][128 * 32];
    __shared__ __align__(16) u16 lsB[2][RROWS * 32];
    const int n = blockIdx.z;
    const u16* Bn = B + (long)n * strideB;
    float* Cn = C + (long)n * strideC;
    const int tid = threadIdx.x;
    const int lane = tid & 63;
    const int wid = tid >> 6;
    const int mw = wid >> 1, nw = wid & 1;
    const int lr = lane & 15, lk = lane >> 4;
    const int rowBase = blockIdx.y * 128;
    const int colBase = blockIdx.x * 128;
    const int g0 = PADDED ? (colBase >> 6) * 66 : colBase;

    // prologue: B first, then A(0), A(1)  (VMCNT(2) at phase 0 leaves A(1))
    STAGE_B(lsB[0], 0);
    STAGE_A(lsA[0], 0, 0);
    STAGE_A(lsA[1], (NT > 1 ? 1 : 0), (NT > 1 ? 0 : 1));

    const int aswz = (lk ^ ((lr >> 1) & 3)) << 3;
    int aoff[4];
#pragma unroll
    for (int mf = 0; mf < 4; ++mf)
        aoff[mf] = (mw * 64 + mf * 16 + lr) * 32 + aswz;

    f32x4 acc[4][4] = {};
    for (int kx = 0; kx < NKX; ++kx) {
        const u16* lb = lsB[kx & 1];
#pragma unroll
        for (int t = 0; t < NT; ++t) {
            const int s = kx * NT + t;
            if (s == S - 1) { VMCNT(0); } else { VMCNT(2); }
            __builtin_amdgcn_s_barrier();
            asm volatile("" ::: "memory");
            // post-barrier issues (WAR-safe: no wave pre-barrier now)
            if (s + 2 < S) {
                const int s2 = s + 2;
                const int kx2 = s2 / NT;
                const int t2 = s2 - kx2 * NT;
                STAGE_A(lsA[s2 % 3], t2, kx2);
            }
            if (t == 0 && kx + 1 < NKX) STAGE_B(lsB[(kx + 1) & 1], kx + 1);

            const u16* la = lsA[s % 3];
            bf16x8 af[4], bfr[4];
#pragma unroll
            for (int mf = 0; mf < 4; ++mf)
                af[mf] = *(const bf16x8*)(la + aoff[mf]);
            int rb;
            if (PADDED) {
                int dh = t / 3 - 1, dw = t - (t / 3) * 3 - 1;
                rb = (nw + dh + 1) * 66 + dw + 1 + lr;
            } else {
                rb = nw * 64 + lr;
            }
            const int bswz = (lk ^ ((rb >> 1) & 3)) << 3;
#pragma unroll
            for (int nf = 0; nf < 4; ++nf)
                bfr[nf] = *(const bf16x8*)(lb + (rb + nf * 16) * 32 + bswz);
#pragma unroll
            for (int mf = 0; mf < 4; ++mf)
#pragma unroll
                for (int nf = 0; nf < 4; ++nf)
                    acc[mf][nf] = __builtin_amdgcn_mfma_f32_16x16x32_bf16(
                        af[mf], bfr[nf], acc[mf][nf], 0, 0, 0);
        }
    }

#pragma unroll
    for (int mf = 0; mf < 4; ++mf) {
#pragma unroll
        for (int reg = 0; reg < 4; ++reg) {
            int co = rowBase + mw * 64 + mf * 16 + lk * 4 + reg;
            float sc = scale[co], sh = shift[co];
#pragma unroll
            for (int nf = 0; nf < 4; ++nf) {
                int col = colBase + nw * 64 + nf * 16 + lr;
                float y = acc[mf][nf][reg] * sc + sh;
                if (silu) y = y / (1.f + expf(-y));
                Cn[(long)co * 4096 + col] = y;
            }
        }
    }
}

// ---------------- prep kernels ----------------
__global__ __launch_bounds__(256) void prep_w_kernel(
    const float* __restrict__ w_conv, const float* __restrict__ w_up,
    const float* __restrict__ w_enc, const float* __restrict__ w_down,
    u16* __restrict__ wT, u16* __restrict__ wupT, u16* __restrict__ wencT,
    u16* __restrict__ wdT)
{
    int gid = blockIdx.x * 256 + threadIdx.x;
    if (gid < 589824) {             // wT[t][co][ci] = w_conv[co][ci][t]
        int t = gid >> 16;
        int co = (gid >> 8) & 255;
        int ci = gid & 255;
        wT[gid] = f2bf(w_conv[(co * 256 + ci) * 9 + t]);
    }
    if (gid < 131072) wupT[gid] = f2bf(w_up[gid]);
    if (gid < 73728) {              // wencT[t][co<64][ci] (zeros co>=36)
        int t = gid >> 13;
        int co = (gid >> 7) & 63;
        int ci = gid & 127;
        wencT[gid] = (co < 36) ? f2bf(w_enc[(co * 128 + ci) * 9 + t]) : (u16)0;
    }
    if (gid < 65536) wdT[gid] = f2bf(w_down[gid]);
}

__global__ void prep_bn_kernel(const float* __restrict__ bn_conv,
                               const float* __restrict__ b_up,
                               const float* __restrict__ w_l2,
                               float* __restrict__ bnp, float* __restrict__ wl2T)
{
    int i = threadIdx.x;            // 256
    float g = bn_conv[i], b = bn_conv[256 + i], m = bn_conv[512 + i], v = bn_conv[768 + i];
    float sc = g * rsqrtf(v + EPS);
    bnp[i] = sc;
    bnp[256 + i] = b - m * sc;
    bnp[768 + i] = b_up[i];
    if (i < 8) {                    // c2[j] = w_l2[j] . b_up
        float s = 0.f;
        for (int co = 0; co < 256; ++co) s += w_l2[i * 256 + co] * b_up[co];
        bnp[512 + i] = s;
    }
#pragma unroll
    for (int j = 0; j < 8; ++j)     // wl2T[co][j]
        wl2T[i * 8 + j] = w_l2[j * 256 + i];
}

extern "C" void kernel_launch(void* const* d_in, const int* in_sizes, int n_in,
                              void* d_out, int out_size, void* d_ws, size_t ws_size,
                              hipStream_t stream)
{
    const float* input1 = (const float*)d_in[0];
    const float* input2 = (const float*)d_in[1];
    const float* w_down = (const float*)d_in[2];
    const float* b_down = (const float*)d_in[3];
    const float* w_enc  = (const float*)d_in[4];
    const float* b_enc  = (const float*)d_in[5];
    const float* w_up   = (const float*)d_in[6];
    const float* b_up   = (const float*)d_in[7];
    const float* w_l1   = (const float*)d_in[8];
    const float* bn_l1  = (const float*)d_in[9];
    const float* w_l2   = (const float*)d_in[10];
    const float* bn_l2  = (const float*)d_in[11];
    const float* w_wl   = (const float*)d_in[12];
    const float* b_wl   = (const float*)d_in[13];
    const float* w_conv = (const float*)d_in[14];
    const float* bn_conv= (const float*)d_in[15];
    float* out = (float*)d_out;

    // workspace layout (float units). ~38 MB total.
    float* ws     = (float*)d_ws;
    float* ktTf   = ws;                      //   591,872 f : ktT bf16 [n][1156][128]
    float* wencTf = ktTf + 591872;           //    36,864 f
    float* kt2    = wencTf + 36864;          //   294,912 f
    float* maskb  = kt2 + 294912;            //   294,912 f
    float* in2Tf  = maskb + 294912;          // 2,097,152 f : in2T bf16 [n][1024][512]
    float* zbfTf  = in2Tf + 2097152;         // 1,048,576 f : zbfT bf16 [n][1024][256]
    float* zwT    = zbfTf + 1048576;         //    65,536 f : [n][1024][8] fp32
    float* lw0g   = zwT + 65536;             //    32,768 f : [n][4096]
    float* ftbf   = lw0g + 32768;            // 4,460,544 f : fusedT bf16 [n][4356][256]
    float* wTf    = ftbf + 4460544;          //   294,912 f
    float* wupTf  = wTf + 294912;            //    65,536 f
    float* wdTf   = wupTf + 65536;           //    32,768 f
    float* wl2T   = wdTf + 32768;            //     2,048 f
    float* bnp    = wl2T + 2048;             //     1,024 f
    u16* ktT      = (u16*)ktTf;
    u16* wencT    = (u16*)wencTf;
    u16* in2T     = (u16*)in2Tf;
    u16* zbfT     = (u16*)zbfTf;
    u16* ftb      = (u16*)ftbf;
    u16* wT       = (u16*)wTf;
    u16* wupT     = (u16*)wupTf;
    u16* wdT      = (u16*)wdTf;

    // prep (independent)
    prep_w_kernel<<<dim3(2304), 256, 0, stream>>>(w_conv, w_up, w_enc, w_down,
                                                  wT, wupT, wencT, wdT);
    prep_bn_kernel<<<dim3(1), 256, 0, stream>>>(bn_conv, b_up, w_l2, bnp, wl2T);
    border_zero_kernel<<<dim3(260), 256, 0, stream>>>(ftb);
    hipMemsetAsync(ktT, 0, 8L * 1156 * 128 * 2, stream);

    // in2T (feeds lowres_gemm)
    in2t_kernel<<<dim3(16, 8), 256, 0, stream>>>(input2, in2T);

    // merged lowres GEMM: zbfT (y<2) + ktT (y==2)
    lowres_gemm_kernel<<<dim3(8, 3, 8), 256, 0, stream>>>(
        wupT, wdT, in2T, b_down, zbfT, ktT);

    // mask pipeline
    enc_mfma_kernel<<<dim3(64, 8), 64, 0, stream>>>(wencT, ktT, b_enc, kt2);
    mask_softmax_kernel<<<dim3(128), 256, 0, stream>>>(kt2, maskb);

    // zw
    zw_kernel<<<dim3(2048), 256, 0, stream>>>(zbfT, wl2T, zwT);

    // level weights -> lw0 (reads i1 once)
    fuse_weights_kernel<<<dim3(512), 256, 0, stream>>>(
        input1, zwT, maskb, bnp, w_l1, bn_l1, bn_l2, w_wl, b_wl, lw0g);

    // CARAFE + blend -> fusedT
    carafe_blend_kernel<<<dim3(128, 8), 256, 0, stream>>>(
        input1, zbfT, maskb, lw0g, bnp, ftb);

    // K7: final conv + BN + SiLU
    gemm_m97_kernel<256, 9, true><<<dim3(32, 2, 8), 256, 0, stream>>>(
        wT, ftb, bnp, bnp + 256, out, 4356L * 256, 256L * 4096, 1);
}

// Round 18
// 160.224 us; speedup vs baseline: 1.0948x; 1.0285x over previous
//
#include <hip/hip_runtime.h>
#include <math.h>

// ASFF_2: N=8, C1=256, C2=512, H=64, W=64, low-res 32x32.
// CARAFE-commutation: u = CARAFE(z)+b_up with z = w_up@in2 (low-res GEMM);
// v2 = CARAFE(zw)+c2 with zw = w_l2@z, c2 = w_l2@b_up.
//  in2t: input2 -> in2T bf16 [n][1024][512]  (64-px tiles, 256B-coalesced)
//  lowres_gemm (merged): y<2 -> zbfT = bf16(w_up @ in2T); y==2 -> ktT
//  enc_mfma -> kt2 ; softmax -> maskb
//  zw: zwT[n][1024][8] = w_l2 @ z
//  carafe_fuse_blend (merged): v1=w_l1@i1 in-block, v2=CARAFE(zw)+c2 -> lw0;
//      u=CARAFE(z)+b_up; blend -> fusedT bf16 [66x66][256]
//      (i1 read once from HBM; pass2 re-read is L2-hot; NO in-block zw dots)
//  K7: m97 GEMM, post-barrier 2-phase-deep A staging (round-15 proven).

#define EPS 1e-5f
typedef unsigned short u16;
typedef __attribute__((ext_vector_type(8))) __bf16 bf16x8;
typedef __attribute__((ext_vector_type(4))) float f32x4;

#define VMCNT(N) asm volatile("s_waitcnt vmcnt(" #N ")" ::: "memory")

__device__ inline u16 f2bf(float x) {
    union { float f; unsigned u; } v; v.f = x;
    unsigned r = v.u + 0x7FFF + ((v.u >> 16) & 1);
    return (u16)(r >> 16);
}
__device__ inline float bf2f(u16 x) {
    union { unsigned u; float f; } v; v.u = (unsigned)x << 16; return v.f;
}

// ---------------- in2t: transpose-cast input2 [512][1024] -> in2T bf16 [q][512] ----------------
__global__ __launch_bounds__(256) void in2t_kernel(
    const float* __restrict__ src0, u16* __restrict__ dst)
{
    constexpr int CP = 516;
    __shared__ u16 lds[64 * CP];
    const int n = blockIdx.y;
    const int p0 = blockIdx.x * 64;
    const int tid = threadIdx.x;
    {
        const int px = tid & 63;
        const float* src = src0 + (long)n * 512 * 1024 + p0 + px;
        for (int ci = tid >> 6; ci < 512; ci += 4)
            lds[px * CP + ci] = f2bf(src[(long)ci * 1024]);
    }
    __syncthreads();
    const int px = tid >> 2;
    const int qd = tid & 3;
    u16* drow = dst + ((long)n * 1024 + p0 + px) * 512;
    const u16* lrow = lds + px * CP;
#pragma unroll
    for (int j = 0; j < 16; ++j) {
        int off = j * 32 + qd * 8;
        *(uint4*)(drow + off) = *(const uint4*)(lrow + off);
    }
}

// ---------------- staging macros ----------------
#define STAGE_A(dstp, t, kx)                                                         \
    {                                                                                \
        const u16* Abase = A + ((long)(t) * 256 + rowBase) * KCC + (kx) * 32;        \
        _Pragma("unroll")                                                            \
        for (int ii = 0; ii < 2; ++ii) {                                             \
            int f = ii * 256 + tid;                                                  \
            int r = f >> 2, uu = f & 3;                                              \
            __builtin_amdgcn_global_load_lds(                                        \
                (const __attribute__((address_space(1))) void*)                      \
                    (Abase + (long)r * KCC + ((uu ^ ((r >> 1) & 3)) << 3)),          \
                (__attribute__((address_space(3))) void*)((dstp) + f * 8),           \
                16, 0, 0);                                                           \
        }                                                                            \
    }

#define STAGE_B(dstp, kx)                                                            \
    {                                                                                \
        const u16* Bbase = Bn + (long)g0 * KCC + (kx) * 32;                          \
        for (int f = tid; f < BUNITS; f += 256) {                                    \
            int r = f >> 2, uu = f & 3;                                              \
            __builtin_amdgcn_global_load_lds(                                        \
                (const __attribute__((address_space(1))) void*)                      \
                    (Bbase + (long)r * KCC + ((uu ^ ((r >> 1) & 3)) << 3)),          \
                (__attribute__((address_space(3))) void*)((dstp) + f * 8),           \
                16, 0, 0);                                                           \
        }                                                                            \
    }

// ---------------- lowres_gemm (merged zgemm + down_mfma) ----------------
__global__ __launch_bounds__(256, 2) void lowres_gemm_kernel(
    const u16* __restrict__ Aup,    // wupT [256][512]
    const u16* __restrict__ Adn,    // wdT  [128][512]
    const u16* __restrict__ B,      // in2T [n][1024][512]
    const float* __restrict__ bias, // b_down
    u16* __restrict__ Z,            // zbfT [n][1024][256]
    u16* __restrict__ ktT)          // [n][1156][128] padded
{
    constexpr int KCC = 512;
    constexpr int BUNITS = 512;
    __shared__ __align__(16) u16 lsA[3][128 * 32];
    __shared__ __align__(16) u16 lsB[3][128 * 32];
    const int n = blockIdx.z;
    const u16* Bn = B + (long)n * 1024 * 512;
    const int tid = threadIdx.x;
    const int lane = tid & 63;
    const int wid = tid >> 6;
    const int mw = wid >> 1, nw = wid & 1;
    const int lr = lane & 15, lk = lane >> 4;
    const int ybr = blockIdx.y;
    const u16* A = (ybr < 2) ? Aup : Adn;
    const int rowBase = (ybr < 2) ? ybr * 128 : 0;
    const int colBase = blockIdx.x * 128;
    const int g0 = colBase;

    STAGE_A(lsA[0], 0, 0); STAGE_B(lsB[0], 0);
    STAGE_A(lsA[1], 0, 1); STAGE_B(lsB[1], 1);

    const int aswz = (lk ^ ((lr >> 1) & 3)) << 3;
    int aoff[4];
#pragma unroll
    for (int mf = 0; mf < 4; ++mf)
        aoff[mf] = (mw * 64 + mf * 16 + lr) * 32 + aswz;

    f32x4 acc[4][4] = {};
    for (int kx = 0; kx < 16; ++kx) {
        if (kx == 15) { VMCNT(0); } else { VMCNT(4); }
        __builtin_amdgcn_s_barrier();
        asm volatile("" ::: "memory");
        if (kx + 2 < 16) {
            STAGE_A(lsA[(kx + 2) % 3], 0, kx + 2);
            STAGE_B(lsB[(kx + 2) % 3], kx + 2);
        }
        const u16* la = lsA[kx % 3];
        const u16* lb = lsB[kx % 3];
        bf16x8 af[4], bfr[4];
#pragma unroll
        for (int mf = 0; mf < 4; ++mf)
            af[mf] = *(const bf16x8*)(la + aoff[mf]);
        const int rb = nw * 64 + lr;
        const int bswz = (lk ^ ((rb >> 1) & 3)) << 3;
#pragma unroll
        for (int nf = 0; nf < 4; ++nf)
            bfr[nf] = *(const bf16x8*)(lb + (rb + nf * 16) * 32 + bswz);
#pragma unroll
        for (int mf = 0; mf < 4; ++mf)
#pragma unroll
            for (int nf = 0; nf < 4; ++nf)
                acc[mf][nf] = __builtin_amdgcn_mfma_f32_16x16x32_bf16(
                    af[mf], bfr[nf], acc[mf][nf], 0, 0, 0);
    }

    if (ybr < 2) {
        u16* Zn = Z + (long)n * 1024 * 256;
#pragma unroll
        for (int mf = 0; mf < 4; ++mf) {
            const int co0 = rowBase + mw * 64 + mf * 16 + lk * 4;
#pragma unroll
            for (int nf = 0; nf < 4; ++nf) {
                const int col = colBase + nw * 64 + nf * 16 + lr;
                unsigned lo = (unsigned)f2bf(acc[mf][nf][0]) |
                              ((unsigned)f2bf(acc[mf][nf][1]) << 16);
                unsigned hi = (unsigned)f2bf(acc[mf][nf][2]) |
                              ((unsigned)f2bf(acc[mf][nf][3]) << 16);
                *(uint2*)(Zn + (long)col * 256 + co0) = make_uint2(lo, hi);
            }
        }
    } else {
        u16* Kn = ktT + (long)n * 1156 * 128;
#pragma unroll
        for (int mf = 0; mf < 4; ++mf) {
            const int co0 = mw * 64 + mf * 16 + lk * 4;     // 0..124
            float b0 = bias[co0], b1 = bias[co0 + 1], b2 = bias[co0 + 2], b3 = bias[co0 + 3];
#pragma unroll
            for (int nf = 0; nf < 4; ++nf) {
                const int col = colBase + nw * 64 + nf * 16 + lr;   // 0..1023
                const int pr = ((col >> 5) + 1) * 34 + (col & 31) + 1;
                unsigned lo = (unsigned)f2bf(acc[mf][nf][0] + b0) |
                              ((unsigned)f2bf(acc[mf][nf][1] + b1) << 16);
                unsigned hi = (unsigned)f2bf(acc[mf][nf][2] + b2) |
                              ((unsigned)f2bf(acc[mf][nf][3] + b3) << 16);
                *(uint2*)(Kn + (long)pr * 128 + co0) = make_uint2(lo, hi);
            }
        }
    }
}

// ---------------- enc_mfma: encoder conv as 9-tap shifted MFMA GEMM ----------------
__global__ __launch_bounds__(64) void enc_mfma_kernel(
    const u16* __restrict__ A, const u16* __restrict__ B,
    const float* __restrict__ bias, float* __restrict__ C)
{
    const int n = blockIdx.y;
    const int lane = threadIdx.x;
    const int lr = lane & 15, lk = lane >> 4;
    const int p = blockIdx.x * 16 + lr;
    const int pr = ((p >> 5) + 1) * 34 + (p & 31) + 1;
    const u16* Bn = B + (long)n * 1156 * 128;
    const int bOff = pr * 128 + lk * 8;
    f32x4 acc[3] = {};
    for (int t = 0; t < 9; ++t) {
        const u16* At = A + t * 8192;
        const int btap = ((t / 3 - 1) * 34 + (t % 3 - 1)) * 128;
#pragma unroll
        for (int k0 = 0; k0 < 128; k0 += 32) {
            bf16x8 bf = *(const bf16x8*)(Bn + bOff + btap + k0);
#pragma unroll
            for (int mf = 0; mf < 3; ++mf) {
                bf16x8 af = *(const bf16x8*)(At + (mf * 16 + lr) * 128 + lk * 8 + k0);
                acc[mf] = __builtin_amdgcn_mfma_f32_16x16x32_bf16(af, bf, acc[mf], 0, 0, 0);
            }
        }
    }
    float* Cn = C + (long)n * 36 * 1024;
#pragma unroll
    for (int mf = 0; mf < 3; ++mf)
#pragma unroll
        for (int reg = 0; reg < 4; ++reg) {
            int co = mf * 16 + lk * 4 + reg;
            if (co < 36)
                Cn[(long)co * 1024 + p] = acc[mf][reg] + bias[co];
        }
}

// ---------------- softmax over k=9 ----------------
__global__ __launch_bounds__(256) void mask_softmax_kernel(
    const float* __restrict__ kt2, float* __restrict__ mask)
{
    int gid = blockIdx.x * 256 + threadIdx.x;   // N*1024*4
    int q = gid & 3;
    int p = (gid >> 2) & 1023;
    int n = gid >> 12;
    float s[9];
    float mx = -1e30f;
#pragma unroll
    for (int k = 0; k < 9; ++k) {
        s[k] = kt2[(long)(n * 36 + k * 4 + q) * 1024 + p];
        mx = fmaxf(mx, s[k]);
    }
    float sum = 0.f;
#pragma unroll
    for (int k = 0; k < 9; ++k) { s[k] = expf(s[k] - mx); sum += s[k]; }
    float inv = 1.f / sum;
    float* mp = mask + (long)(n * 1024 + p) * 36 + q;
#pragma unroll
    for (int k = 0; k < 9; ++k) mp[k * 4] = s[k] * inv;
}

// ---------------- zw: one wave per low-res pixel, butterfly reduce ----------------
__global__ __launch_bounds__(256) void zw_kernel(
    const u16* __restrict__ zbfT, const float* __restrict__ wl2T,
    float* __restrict__ zwT)
{
    const int Q = (blockIdx.x * 256 + threadIdx.x) >> 6;   // 0..8191
    const int lane = threadIdx.x & 63;
    const int ci0 = lane * 4;
    uint2 v = *(const uint2*)(zbfT + (long)Q * 256 + ci0);
    float c[4] = { bf2f((u16)(v.x & 0xffff)), bf2f((u16)(v.x >> 16)),
                   bf2f((u16)(v.y & 0xffff)), bf2f((u16)(v.y >> 16)) };
    float s[8] = {};
#pragma unroll
    for (int t = 0; t < 4; ++t) {
        const float* wr = wl2T + (ci0 + t) * 8;
        float4 wa = *(const float4*)wr;
        float4 wb = *(const float4*)(wr + 4);
        s[0] += wa.x * c[t]; s[1] += wa.y * c[t]; s[2] += wa.z * c[t]; s[3] += wa.w * c[t];
        s[4] += wb.x * c[t]; s[5] += wb.y * c[t]; s[6] += wb.z * c[t]; s[7] += wb.w * c[t];
    }
#pragma unroll
    for (int off = 1; off < 64; off <<= 1)
#pragma unroll
        for (int j = 0; j < 8; ++j)
            s[j] += __shfl_xor(s[j], off, 64);
    if (lane == 0) {
        float* o = zwT + (long)Q * 8;
        *(float4*)o = make_float4(s[0], s[1], s[2], s[3]);
        *(float4*)(o + 4) = make_float4(s[4], s[5], s[6], s[7]);
    }
}

// ---------------- border_zero ----------------
__global__ __launch_bounds__(256) void border_zero_kernel(u16* __restrict__ ftb)
{
    int gid = blockIdx.x * 256 + threadIdx.x;   // 8 * 260 * 32 uint4
    if (gid >= 8 * 260 * 32) return;
    int n = gid / (260 * 32);
    int rem = gid - n * (260 * 32);
    int r = rem >> 5;
    int i = rem & 31;
    int h, w;
    if (r < 66)       { h = 0;  w = r; }
    else if (r < 132) { h = 65; w = r - 66; }
    else { int j = r - 132; h = 1 + (j >> 1); w = (j & 1) * 65; }
    long prow = (long)h * 66 + w;
    uint4* dst = (uint4*)(ftb + (long)n * 4356 * 256 + prow * 256) + i;
    *dst = make_uint4(0, 0, 0, 0);
}

// ---------------- carafe_fuse_blend: v1 in-block -> lw0 ; u=CARAFE(z)+b_up ; blend ----------------
// 32 px / block, 3 blocks/CU (~49 KB LDS). zw comes PRECOMPUTED (round-13 lesson:
// no in-block 256-ch dot products). red scratch unions with lds2 (disjoint in time).
__global__ __launch_bounds__(256) void carafe_fuse_blend_kernel(
    const float* __restrict__ i1g, const u16* __restrict__ zbfT,
    const float* __restrict__ zwT, const float* __restrict__ maskb,
    const float* __restrict__ bnp,          // 512..519 c2, 768.. b_up
    const float* __restrict__ w_l1, const float* __restrict__ bn_l1,
    const float* __restrict__ bn_l2, const float* __restrict__ w_wl,
    const float* __restrict__ b_wl, u16* __restrict__ dst)
{
    __shared__ __align__(16) u16 zbf[54 * 264];     // 27.8 KB
    __shared__ float mlds[16 * 36];                 // 2.3 KB
    __shared__ float zwl[54 * 8];                   // 1.7 KB
    __shared__ float lw0s[32];
    __shared__ __align__(16) unsigned char uscr[32 * 264 * 2];  // 16.5 KB union
    float* red = (float*)uscr;                      // [8][32][8] = 8 KB
    u16* lds2 = (u16*)uscr;                         // [32][264]
    const int n = blockIdx.y;
    const int h = blockIdx.x >> 1;
    const int w0 = (blockIdx.x & 1) << 5;
    const int hq = h >> 1;
    const int wq0 = w0 >> 1;
    const int tid = threadIdx.x;

    // ---- stage z tile, mask row, zw tile ----
    for (int idx = tid; idx < 54 * 32; idx += 256) {
        int px = idx >> 5, unit = idx & 31;
        int r = px / 18, c = px - r * 18;
        int gr = hq - 1 + r, gc = wq0 - 1 + c;
        uint4 v = make_uint4(0u, 0u, 0u, 0u);
        if (gr >= 0 && gr < 32 && gc >= 0 && gc < 32)
            v = *(const uint4*)(zbfT + ((long)n * 1024 + gr * 32 + gc) * 256 + unit * 8);
        *(uint4*)(zbf + px * 264 + unit * 8) = v;
    }
    for (int idx = tid; idx < 576; idx += 256)
        mlds[idx] = maskb[((long)n * 1024 + hq * 32 + wq0) * 36 + idx];
    for (int idx = tid; idx < 432; idx += 256) {
        int px = idx >> 3, j = idx & 7;
        int r = px / 18, c = px - r * 18;
        int gr = hq - 1 + r, gc = wq0 - 1 + c;
        zwl[idx] = (gr >= 0 && gr < 32 && gc >= 0 && gc < 32)
                 ? zwT[((long)n * 1024 + gr * 32 + gc) * 8 + j] : 0.f;
    }

    const int w = tid & 31;
    const int chunk = tid >> 5;
    const float* i1 = i1g + (long)n * 256 * 4096 + (h << 6) + w0 + w;
    {   // pass1: v1 partials (i1 HBM read #1)
        float s1[8] = {};
        for (int ci = chunk * 32; ci < chunk * 32 + 32; ++ci) {
            float x1 = i1[(long)ci * 4096];
#pragma unroll
            for (int j = 0; j < 8; ++j) s1[j] += w_l1[j * 256 + ci] * x1;
        }
#pragma unroll
        for (int j = 0; j < 8; ++j) red[(chunk * 32 + w) * 8 + j] = s1[j];
    }
    __syncthreads();
    {   // reduce over 8 chunks: 256 cells, one per thread (each thread owns its cell)
        int px = tid >> 3, j = tid & 7;
        float s = 0.f;
#pragma unroll
        for (int o = 0; o < 8; ++o) s += red[(o * 32 + px) * 8 + j];
        red[px * 8 + j] = s;
    }
    __syncthreads();
    if (tid < 32) {     // lw0 per pixel
        const int wp = w0 + tid;
        const int wqm = (wp >> 1) - wq0;        // 0..15
        const int q = ((h & 1) << 1) | (wp & 1);
        float m9[9];
#pragma unroll
        for (int k = 0; k < 9; ++k) m9[k] = mlds[wqm * 36 + k * 4 + q];
        float v[16];
#pragma unroll
        for (int j = 0; j < 8; ++j) v[j] = red[tid * 8 + j];
#pragma unroll
        for (int j = 0; j < 8; ++j) v[8 + j] = bnp[512 + j];   // c2
#pragma unroll
        for (int k = 0; k < 9; ++k) {
            int dh = k / 3 - 1, dw = k - (k / 3) * 3 - 1;
            const float* zp = zwl + ((1 + dh) * 18 + wqm + 1 + dw) * 8;
            float mk = m9[k];
#pragma unroll
            for (int j = 0; j < 8; ++j) v[8 + j] += mk * zp[j];
        }
        float z0 = b_wl[0], z1 = b_wl[1];
#pragma unroll
        for (int j = 0; j < 8; ++j) {
            float g = bn_l1[j], b = bn_l1[8 + j], m = bn_l1[16 + j], va = bn_l1[24 + j];
            float y = (v[j] - m) * (g * rsqrtf(va + EPS)) + b;
            float sv = y / (1.f + expf(-y));
            z0 += w_wl[j] * sv;
            z1 += w_wl[16 + j] * sv;
            g = bn_l2[j]; b = bn_l2[8 + j]; m = bn_l2[16 + j]; va = bn_l2[24 + j];
            y = (v[8 + j] - m) * (g * rsqrtf(va + EPS)) + b;
            sv = y / (1.f + expf(-y));
            z0 += w_wl[8 + j] * sv;
            z1 += w_wl[24 + j] * sv;
        }
        lw0s[tid] = 1.f / (1.f + expf(z1 - z0));
    }
    __syncthreads();
    {   // pass2: u = CARAFE(z)+b_up ; blend (i1 re-read L2-hot) ; bf16 into lds2
        const float lw = lw0s[w], lw1 = 1.f - lw;
        const int wp = w0 + w;
        const int wqm = (wp >> 1) - wq0;
        const int q = ((h & 1) << 1) | (wp & 1);
        float m9[9];
#pragma unroll
        for (int k = 0; k < 9; ++k) m9[k] = mlds[wqm * 36 + k * 4 + q];
        for (int ci = chunk * 32; ci < chunk * 32 + 32; ci += 8) {
            float uu[8];
            {
                float4 ba = *(const float4*)(bnp + 768 + ci);
                float4 bb = *(const float4*)(bnp + 768 + ci + 4);
                uu[0] = ba.x; uu[1] = ba.y; uu[2] = ba.z; uu[3] = ba.w;
                uu[4] = bb.x; uu[5] = bb.y; uu[6] = bb.z; uu[7] = bb.w;
            }
#pragma unroll
            for (int k = 0; k < 9; ++k) {
                int dh = k / 3 - 1, dw = k - (k / 3) * 3 - 1;
                uint4 vz = *(const uint4*)(zbf + ((1 + dh) * 18 + wqm + 1 + dw) * 264 + ci);
                float mk = m9[k];
                uu[0] += mk * bf2f((u16)(vz.x & 0xffff));
                uu[1] += mk * bf2f((u16)(vz.x >> 16));
                uu[2] += mk * bf2f((u16)(vz.y & 0xffff));
                uu[3] += mk * bf2f((u16)(vz.y >> 16));
                uu[4] += mk * bf2f((u16)(vz.z & 0xffff));
                uu[5] += mk * bf2f((u16)(vz.z >> 16));
                uu[6] += mk * bf2f((u16)(vz.w & 0xffff));
                uu[7] += mk * bf2f((u16)(vz.w >> 16));
            }
            unsigned o0 = (unsigned)f2bf(i1[(long)ci * 4096] * lw + uu[0] * lw1)
                        | ((unsigned)f2bf(i1[(long)(ci + 1) * 4096] * lw + uu[1] * lw1) << 16);
            unsigned o1 = (unsigned)f2bf(i1[(long)(ci + 2) * 4096] * lw + uu[2] * lw1)
                        | ((unsigned)f2bf(i1[(long)(ci + 3) * 4096] * lw + uu[3] * lw1) << 16);
            unsigned o2 = (unsigned)f2bf(i1[(long)(ci + 4) * 4096] * lw + uu[4] * lw1)
                        | ((unsigned)f2bf(i1[(long)(ci + 5) * 4096] * lw + uu[5] * lw1) << 16);
            unsigned o3 = (unsigned)f2bf(i1[(long)(ci + 6) * 4096] * lw + uu[6] * lw1)
                        | ((unsigned)f2bf(i1[(long)(ci + 7) * 4096] * lw + uu[7] * lw1) << 16);
            *(uint4*)(lds2 + w * 264 + ci) = make_uint4(o0, o1, o2, o3);
        }
    }
    __syncthreads();
    {   // transposed padded write
        const int px = tid >> 3, qd = tid & 7;
        const int pg = (h << 6) + w0 + px;
        long prow = (long)((pg >> 6) + 1) * 66 + (pg & 63) + 1;
        u16* drow = dst + (long)n * 4356 * 256 + prow * 256;
        const u16* lrow = lds2 + px * 264;
#pragma unroll
        for (int j = 0; j < 16; ++j) {
            int off = j * 16 + qd * 2;
            *(unsigned*)(drow + off) = *(const unsigned*)(lrow + off);
        }
    }
}

// ---------------- K7: m97 GEMM — post-barrier 2-deep A staging (round-15 proven) ----------------
template<int KCC, int NT, bool PADDED>
__global__ __launch_bounds__(256, 2) void gemm_m97_kernel(
    const u16* __restrict__ A,      // [NT][256][KCC] bf16
    const u16* __restrict__ B,      // per image [rows][KCC] bf16
    const float* __restrict__ scale, const float* __restrict__ shift,
    float* __restrict__ C, long strideB, long strideC, int silu)
{
    constexpr int RROWS = PADDED ? 264 : 128;
    constexpr int BUNITS = RROWS * 4;
    constexpr int NKX = KCC / 32;
    constexpr int S = NKX * NT;
    __shared__ __align__(16) u16 lsA[3][128 * 32];
    __shared__ __align__(16) u16 lsB[2][RROWS * 32];
    const int n = blockIdx.z;
    const u16* Bn = B + (long)n * strideB;
    float* Cn = C + (long)n * strideC;
    const int tid = threadIdx.x;
    const int lane = tid & 63;
    const int wid = tid >> 6;
    const int mw = wid >> 1, nw = wid & 1;
    const int lr = lane & 15, lk = lane >> 4;
    const int rowBase = blockIdx.y * 128;
    const int colBase = blockIdx.x * 128;
    const int g0 = PADDED ? (colBase >> 6) * 66 : colBase;

    STAGE_B(lsB[0], 0);
    STAGE_A(lsA[0], 0, 0);
    STAGE_A(lsA[1], (NT > 1 ? 1 : 0), (NT > 1 ? 0 : 1));

    const int aswz = (lk ^ ((lr >> 1) & 3)) << 3;
    int aoff[4];
#pragma unroll
    for (int mf = 0; mf < 4; ++mf)
        aoff[mf] = (mw * 64 + mf * 16 + lr) * 32 + aswz;

    f32x4 acc[4][4] = {};
    for (int kx = 0; kx < NKX; ++kx) {
        const u16* lb = lsB[kx & 1];
#pragma unroll
        for (int t = 0; t < NT; ++t) {
            const int s = kx * NT + t;
            if (s == S - 1) { VMCNT(0); } else { VMCNT(2); }
            __builtin_amdgcn_s_barrier();
            asm volatile("" ::: "memory");
            if (s + 2 < S) {
                const int s2 = s + 2;
                const int kx2 = s2 / NT;
                const int t2 = s2 - kx2 * NT;
                STAGE_A(lsA[s2 % 3], t2, kx2);
            }
            if (t == 0 && kx + 1 < NKX) STAGE_B(lsB[(kx + 1) & 1], kx + 1);

            const u16* la = lsA[s % 3];
            bf16x8 af[4], bfr[4];
#pragma unroll
            for (int mf = 0; mf < 4; ++mf)
                af[mf] = *(const bf16x8*)(la + aoff[mf]);
            int rb;
            if (PADDED) {
                int dh = t / 3 - 1, dw = t - (t / 3) * 3 - 1;
                rb = (nw + dh + 1) * 66 + dw + 1 + lr;
            } else {
                rb = nw * 64 + lr;
            }
            const int bswz = (lk ^ ((rb >> 1) & 3)) << 3;
#pragma unroll
            for (int nf = 0; nf < 4; ++nf)
                bfr[nf] = *(const bf16x8*)(lb + (rb + nf * 16) * 32 + bswz);
#pragma unroll
            for (int mf = 0; mf < 4; ++mf)
#pragma unroll
                for (int nf = 0; nf < 4; ++nf)
                    acc[mf][nf] = __builtin_amdgcn_mfma_f32_16x16x32_bf16(
                        af[mf], bfr[nf], acc[mf][nf], 0, 0, 0);
        }
    }

#pragma unroll
    for (int mf = 0; mf < 4; ++mf) {
#pragma unroll
        for (int reg = 0; reg < 4; ++reg) {
            int co = rowBase + mw * 64 + mf * 16 + lk * 4 + reg;
            float sc = scale[co], sh = shift[co];
#pragma unroll
            for (int nf = 0; nf < 4; ++nf) {
                int col = colBase + nw * 64 + nf * 16 + lr;
                float y = acc[mf][nf][reg] * sc + sh;
                if (silu) y = y / (1.f + expf(-y));
                Cn[(long)co * 4096 + col] = y;
            }
        }
    }
}

// ---------------- prep kernels ----------------
__global__ __launch_bounds__(256) void prep_w_kernel(
    const float* __restrict__ w_conv, const float* __restrict__ w_up,
    const float* __restrict__ w_enc, const float* __restrict__ w_down,
    u16* __restrict__ wT, u16* __restrict__ wupT, u16* __restrict__ wencT,
    u16* __restrict__ wdT)
{
    int gid = blockIdx.x * 256 + threadIdx.x;
    if (gid < 589824) {             // wT[t][co][ci] = w_conv[co][ci][t]
        int t = gid >> 16;
        int co = (gid >> 8) & 255;
        int ci = gid & 255;
        wT[gid] = f2bf(w_conv[(co * 256 + ci) * 9 + t]);
    }
    if (gid < 131072) wupT[gid] = f2bf(w_up[gid]);
    if (gid < 73728) {              // wencT[t][co<64][ci] (zeros co>=36)
        int t = gid >> 13;
        int co = (gid >> 7) & 63;
        int ci = gid & 127;
        wencT[gid] = (co < 36) ? f2bf(w_enc[(co * 128 + ci) * 9 + t]) : (u16)0;
    }
    if (gid < 65536) wdT[gid] = f2bf(w_down[gid]);
}

__global__ void prep_bn_kernel(const float* __restrict__ bn_conv,
                               const float* __restrict__ b_up,
                               const float* __restrict__ w_l2,
                               float* __restrict__ bnp, float* __restrict__ wl2T)
{
    int i = threadIdx.x;            // 256
    float g = bn_conv[i], b = bn_conv[256 + i], m = bn_conv[512 + i], v = bn_conv[768 + i];
    float sc = g * rsqrtf(v + EPS);
    bnp[i] = sc;
    bnp[256 + i] = b - m * sc;
    bnp[768 + i] = b_up[i];
    if (i < 8) {                    // c2[j] = w_l2[j] . b_up
        float s = 0.f;
        for (int co = 0; co < 256; ++co) s += w_l2[i * 256 + co] * b_up[co];
        bnp[512 + i] = s;
    }
#pragma unroll
    for (int j = 0; j < 8; ++j)     // wl2T[co][j]
        wl2T[i * 8 + j] = w_l2[j * 256 + i];
}

extern "C" void kernel_launch(void* const* d_in, const int* in_sizes, int n_in,
                              void* d_out, int out_size, void* d_ws, size_t ws_size,
                              hipStream_t stream)
{
    const float* input1 = (const float*)d_in[0];
    const float* input2 = (const float*)d_in[1];
    const float* w_down = (const float*)d_in[2];
    const float* b_down = (const float*)d_in[3];
    const float* w_enc  = (const float*)d_in[4];
    const float* b_enc  = (const float*)d_in[5];
    const float* w_up   = (const float*)d_in[6];
    const float* b_up   = (const float*)d_in[7];
    const float* w_l1   = (const float*)d_in[8];
    const float* bn_l1  = (const float*)d_in[9];
    const float* w_l2   = (const float*)d_in[10];
    const float* bn_l2  = (const float*)d_in[11];
    const float* w_wl   = (const float*)d_in[12];
    const float* b_wl   = (const float*)d_in[13];
    const float* w_conv = (const float*)d_in[14];
    const float* bn_conv= (const float*)d_in[15];
    float* out = (float*)d_out;

    // workspace layout (float units). ~38 MB total.
    float* ws     = (float*)d_ws;
    float* ktTf   = ws;                      //   591,872 f : ktT bf16 [n][1156][128]
    float* wencTf = ktTf + 591872;           //    36,864 f
    float* kt2    = wencTf + 36864;          //   294,912 f
    float* maskb  = kt2 + 294912;            //   294,912 f
    float* in2Tf  = maskb + 294912;          // 2,097,152 f : in2T bf16 [n][1024][512]
    float* zbfTf  = in2Tf + 2097152;         // 1,048,576 f : zbfT bf16 [n][1024][256]
    float* zwT    = zbfTf + 1048576;         //    65,536 f : [n][1024][8] fp32
    float* ftbf   = zwT + 65536;             // 4,460,544 f : fusedT bf16 [n][4356][256]
    float* wTf    = ftbf + 4460544;          //   294,912 f
    float* wupTf  = wTf + 294912;            //    65,536 f
    float* wdTf   = wupTf + 65536;           //    32,768 f
    float* wl2T   = wdTf + 32768;            //     2,048 f
    float* bnp    = wl2T + 2048;             //     1,024 f
    u16* ktT      = (u16*)ktTf;
    u16* wencT    = (u16*)wencTf;
    u16* in2T     = (u16*)in2Tf;
    u16* zbfT     = (u16*)zbfTf;
    u16* ftb      = (u16*)ftbf;
    u16* wT       = (u16*)wTf;
    u16* wupT     = (u16*)wupTf;
    u16* wdT      = (u16*)wdTf;

    // prep (independent)
    prep_w_kernel<<<dim3(2304), 256, 0, stream>>>(w_conv, w_up, w_enc, w_down,
                                                  wT, wupT, wencT, wdT);
    prep_bn_kernel<<<dim3(1), 256, 0, stream>>>(bn_conv, b_up, w_l2, bnp, wl2T);
    border_zero_kernel<<<dim3(260), 256, 0, stream>>>(ftb);
    hipMemsetAsync(ktT, 0, 8L * 1156 * 128 * 2, stream);

    // in2T (feeds lowres_gemm)
    in2t_kernel<<<dim3(16, 8), 256, 0, stream>>>(input2, in2T);

    // merged lowres GEMM: zbfT (y<2) + ktT (y==2)
    lowres_gemm_kernel<<<dim3(8, 3, 8), 256, 0, stream>>>(
        wupT, wdT, in2T, b_down, zbfT, ktT);

    // mask pipeline
    enc_mfma_kernel<<<dim3(64, 8), 64, 0, stream>>>(wencT, ktT, b_enc, kt2);
    mask_softmax_kernel<<<dim3(128), 256, 0, stream>>>(kt2, maskb);

    // zw
    zw_kernel<<<dim3(2048), 256, 0, stream>>>(zbfT, wl2T, zwT);

    // merged level-attention + CARAFE + blend -> fusedT
    carafe_fuse_blend_kernel<<<dim3(128, 8), 256, 0, stream>>>(
        input1, zbfT, zwT, maskb, bnp, w_l1, bn_l1, bn_l2, w_wl, b_wl, ftb);

    // K7: final conv + BN + SiLU
    gemm_m97_kernel<256, 9, true><<<dim3(32, 2, 8), 256, 0, stream>>>(
        wT, ftb, bnp, bnp + 256, out, 4356L * 256, 256L * 4096, 1);
}

// Round 19
// 150.248 us; speedup vs baseline: 1.1675x; 1.0664x over previous
//
#include <hip/hip_runtime.h>
#include <math.h>

// ASFF_2: N=8, C1=256, C2=512, H=64, W=64, low-res 32x32.
// CARAFE-commutation: u = CARAFE(z)+b_up with z = w_up@in2 (low-res GEMM);
// v2 = CARAFE(zw)+c2 with zw = w_l2@z, c2 = w_l2@b_up.
//  in2t: input2 -> in2T bf16 [n][1024][512]
//  lowres_gemm (merged): y<2 -> zbfT = bf16(w_up @ in2T); y==2 -> ktT
//  enc_mfma -> kt2 ; softmax -> maskb
//  zw: zwT[n][1024][8] = w_l2 @ z
//  carafe_fuse_blend: v1 in-block -> lw0 ; u=CARAFE(z)+b_up ; blend -> fusedT
//      z/mask/zw read DIRECTLY from L2 (no LDS staging; z is 2MB/img, L2-fits)
//      -> LDS ~17KB -> 7-8 blocks/CU (was 2-3 at 49.6KB)
//  K7: m97 GEMM, post-barrier 2-phase-deep A staging (round-15 proven).

#define EPS 1e-5f
typedef unsigned short u16;
typedef __attribute__((ext_vector_type(8))) __bf16 bf16x8;
typedef __attribute__((ext_vector_type(4))) float f32x4;

#define VMCNT(N) asm volatile("s_waitcnt vmcnt(" #N ")" ::: "memory")

__device__ inline u16 f2bf(float x) {
    union { float f; unsigned u; } v; v.f = x;
    unsigned r = v.u + 0x7FFF + ((v.u >> 16) & 1);
    return (u16)(r >> 16);
}
__device__ inline float bf2f(u16 x) {
    union { unsigned u; float f; } v; v.u = (unsigned)x << 16; return v.f;
}

// ---------------- in2t: transpose-cast input2 [512][1024] -> in2T bf16 [q][512] ----------------
__global__ __launch_bounds__(256) void in2t_kernel(
    const float* __restrict__ src0, u16* __restrict__ dst)
{
    constexpr int CP = 516;
    __shared__ u16 lds[64 * CP];
    const int n = blockIdx.y;
    const int p0 = blockIdx.x * 64;
    const int tid = threadIdx.x;
    {
        const int px = tid & 63;
        const float* src = src0 + (long)n * 512 * 1024 + p0 + px;
        for (int ci = tid >> 6; ci < 512; ci += 4)
            lds[px * CP + ci] = f2bf(src[(long)ci * 1024]);
    }
    __syncthreads();
    const int px = tid >> 2;
    const int qd = tid & 3;
    u16* drow = dst + ((long)n * 1024 + p0 + px) * 512;
    const u16* lrow = lds + px * CP;
#pragma unroll
    for (int j = 0; j < 16; ++j) {
        int off = j * 32 + qd * 8;
        *(uint4*)(drow + off) = *(const uint4*)(lrow + off);
    }
}

// ---------------- staging macros ----------------
#define STAGE_A(dstp, t, kx)                                                         \
    {                                                                                \
        const u16* Abase = A + ((long)(t) * 256 + rowBase) * KCC + (kx) * 32;        \
        _Pragma("unroll")                                                            \
        for (int ii = 0; ii < 2; ++ii) {                                             \
            int f = ii * 256 + tid;                                                  \
            int r = f >> 2, uu = f & 3;                                              \
            __builtin_amdgcn_global_load_lds(                                        \
                (const __attribute__((address_space(1))) void*)                      \
                    (Abase + (long)r * KCC + ((uu ^ ((r >> 1) & 3)) << 3)),          \
                (__attribute__((address_space(3))) void*)((dstp) + f * 8),           \
                16, 0, 0);                                                           \
        }                                                                            \
    }

#define STAGE_B(dstp, kx)                                                            \
    {                                                                                \
        const u16* Bbase = Bn + (long)g0 * KCC + (kx) * 32;                          \
        for (int f = tid; f < BUNITS; f += 256) {                                    \
            int r = f >> 2, uu = f & 3;                                              \
            __builtin_amdgcn_global_load_lds(                                        \
                (const __attribute__((address_space(1))) void*)                      \
                    (Bbase + (long)r * KCC + ((uu ^ ((r >> 1) & 3)) << 3)),          \
                (__attribute__((address_space(3))) void*)((dstp) + f * 8),           \
                16, 0, 0);                                                           \
        }                                                                            \
    }

// ---------------- lowres_gemm (merged zgemm + down_mfma) ----------------
__global__ __launch_bounds__(256, 2) void lowres_gemm_kernel(
    const u16* __restrict__ Aup,    // wupT [256][512]
    const u16* __restrict__ Adn,    // wdT  [128][512]
    const u16* __restrict__ B,      // in2T [n][1024][512]
    const float* __restrict__ bias, // b_down
    u16* __restrict__ Z,            // zbfT [n][1024][256]
    u16* __restrict__ ktT)          // [n][1156][128] padded
{
    constexpr int KCC = 512;
    constexpr int BUNITS = 512;
    __shared__ __align__(16) u16 lsA[3][128 * 32];
    __shared__ __align__(16) u16 lsB[3][128 * 32];
    const int n = blockIdx.z;
    const u16* Bn = B + (long)n * 1024 * 512;
    const int tid = threadIdx.x;
    const int lane = tid & 63;
    const int wid = tid >> 6;
    const int mw = wid >> 1, nw = wid & 1;
    const int lr = lane & 15, lk = lane >> 4;
    const int ybr = blockIdx.y;
    const u16* A = (ybr < 2) ? Aup : Adn;
    const int rowBase = (ybr < 2) ? ybr * 128 : 0;
    const int colBase = blockIdx.x * 128;
    const int g0 = colBase;

    STAGE_A(lsA[0], 0, 0); STAGE_B(lsB[0], 0);
    STAGE_A(lsA[1], 0, 1); STAGE_B(lsB[1], 1);

    const int aswz = (lk ^ ((lr >> 1) & 3)) << 3;
    int aoff[4];
#pragma unroll
    for (int mf = 0; mf < 4; ++mf)
        aoff[mf] = (mw * 64 + mf * 16 + lr) * 32 + aswz;

    f32x4 acc[4][4] = {};
    for (int kx = 0; kx < 16; ++kx) {
        if (kx == 15) { VMCNT(0); } else { VMCNT(4); }
        __builtin_amdgcn_s_barrier();
        asm volatile("" ::: "memory");
        if (kx + 2 < 16) {
            STAGE_A(lsA[(kx + 2) % 3], 0, kx + 2);
            STAGE_B(lsB[(kx + 2) % 3], kx + 2);
        }
        const u16* la = lsA[kx % 3];
        const u16* lb = lsB[kx % 3];
        bf16x8 af[4], bfr[4];
#pragma unroll
        for (int mf = 0; mf < 4; ++mf)
            af[mf] = *(const bf16x8*)(la + aoff[mf]);
        const int rb = nw * 64 + lr;
        const int bswz = (lk ^ ((rb >> 1) & 3)) << 3;
#pragma unroll
        for (int nf = 0; nf < 4; ++nf)
            bfr[nf] = *(const bf16x8*)(lb + (rb + nf * 16) * 32 + bswz);
#pragma unroll
        for (int mf = 0; mf < 4; ++mf)
#pragma unroll
            for (int nf = 0; nf < 4; ++nf)
                acc[mf][nf] = __builtin_amdgcn_mfma_f32_16x16x32_bf16(
                    af[mf], bfr[nf], acc[mf][nf], 0, 0, 0);
    }

    if (ybr < 2) {
        u16* Zn = Z + (long)n * 1024 * 256;
#pragma unroll
        for (int mf = 0; mf < 4; ++mf) {
            const int co0 = rowBase + mw * 64 + mf * 16 + lk * 4;
#pragma unroll
            for (int nf = 0; nf < 4; ++nf) {
                const int col = colBase + nw * 64 + nf * 16 + lr;
                unsigned lo = (unsigned)f2bf(acc[mf][nf][0]) |
                              ((unsigned)f2bf(acc[mf][nf][1]) << 16);
                unsigned hi = (unsigned)f2bf(acc[mf][nf][2]) |
                              ((unsigned)f2bf(acc[mf][nf][3]) << 16);
                *(uint2*)(Zn + (long)col * 256 + co0) = make_uint2(lo, hi);
            }
        }
    } else {
        u16* Kn = ktT + (long)n * 1156 * 128;
#pragma unroll
        for (int mf = 0; mf < 4; ++mf) {
            const int co0 = mw * 64 + mf * 16 + lk * 4;     // 0..124
            float b0 = bias[co0], b1 = bias[co0 + 1], b2 = bias[co0 + 2], b3 = bias[co0 + 3];
#pragma unroll
            for (int nf = 0; nf < 4; ++nf) {
                const int col = colBase + nw * 64 + nf * 16 + lr;   // 0..1023
                const int pr = ((col >> 5) + 1) * 34 + (col & 31) + 1;
                unsigned lo = (unsigned)f2bf(acc[mf][nf][0] + b0) |
                              ((unsigned)f2bf(acc[mf][nf][1] + b1) << 16);
                unsigned hi = (unsigned)f2bf(acc[mf][nf][2] + b2) |
                              ((unsigned)f2bf(acc[mf][nf][3] + b3) << 16);
                *(uint2*)(Kn + (long)pr * 128 + co0) = make_uint2(lo, hi);
            }
        }
    }
}

// ---------------- enc_mfma: encoder conv as 9-tap shifted MFMA GEMM ----------------
__global__ __launch_bounds__(64) void enc_mfma_kernel(
    const u16* __restrict__ A, const u16* __restrict__ B,
    const float* __restrict__ bias, float* __restrict__ C)
{
    const int n = blockIdx.y;
    const int lane = threadIdx.x;
    const int lr = lane & 15, lk = lane >> 4;
    const int p = blockIdx.x * 16 + lr;
    const int pr = ((p >> 5) + 1) * 34 + (p & 31) + 1;
    const u16* Bn = B + (long)n * 1156 * 128;
    const int bOff = pr * 128 + lk * 8;
    f32x4 acc[3] = {};
    for (int t = 0; t < 9; ++t) {
        const u16* At = A + t * 8192;
        const int btap = ((t / 3 - 1) * 34 + (t % 3 - 1)) * 128;
#pragma unroll
        for (int k0 = 0; k0 < 128; k0 += 32) {
            bf16x8 bf = *(const bf16x8*)(Bn + bOff + btap + k0);
#pragma unroll
            for (int mf = 0; mf < 3; ++mf) {
                bf16x8 af = *(const bf16x8*)(At + (mf * 16 + lr) * 128 + lk * 8 + k0);
                acc[mf] = __builtin_amdgcn_mfma_f32_16x16x32_bf16(af, bf, acc[mf], 0, 0, 0);
            }
        }
    }
    float* Cn = C + (long)n * 36 * 1024;
#pragma unroll
    for (int mf = 0; mf < 3; ++mf)
#pragma unroll
        for (int reg = 0; reg < 4; ++reg) {
            int co = mf * 16 + lk * 4 + reg;
            if (co < 36)
                Cn[(long)co * 1024 + p] = acc[mf][reg] + bias[co];
        }
}

// ---------------- softmax over k=9 ----------------
__global__ __launch_bounds__(256) void mask_softmax_kernel(
    const float* __restrict__ kt2, float* __restrict__ mask)
{
    int gid = blockIdx.x * 256 + threadIdx.x;   // N*1024*4
    int q = gid & 3;
    int p = (gid >> 2) & 1023;
    int n = gid >> 12;
    float s[9];
    float mx = -1e30f;
#pragma unroll
    for (int k = 0; k < 9; ++k) {
        s[k] = kt2[(long)(n * 36 + k * 4 + q) * 1024 + p];
        mx = fmaxf(mx, s[k]);
    }
    float sum = 0.f;
#pragma unroll
    for (int k = 0; k < 9; ++k) { s[k] = expf(s[k] - mx); sum += s[k]; }
    float inv = 1.f / sum;
    float* mp = mask + (long)(n * 1024 + p) * 36 + q;
#pragma unroll
    for (int k = 0; k < 9; ++k) mp[k * 4] = s[k] * inv;
}

// ---------------- zw: one wave per low-res pixel, butterfly reduce ----------------
__global__ __launch_bounds__(256) void zw_kernel(
    const u16* __restrict__ zbfT, const float* __restrict__ wl2T,
    float* __restrict__ zwT)
{
    const int Q = (blockIdx.x * 256 + threadIdx.x) >> 6;   // 0..8191
    const int lane = threadIdx.x & 63;
    const int ci0 = lane * 4;
    uint2 v = *(const uint2*)(zbfT + (long)Q * 256 + ci0);
    float c[4] = { bf2f((u16)(v.x & 0xffff)), bf2f((u16)(v.x >> 16)),
                   bf2f((u16)(v.y & 0xffff)), bf2f((u16)(v.y >> 16)) };
    float s[8] = {};
#pragma unroll
    for (int t = 0; t < 4; ++t) {
        const float* wr = wl2T + (ci0 + t) * 8;
        float4 wa = *(const float4*)wr;
        float4 wb = *(const float4*)(wr + 4);
        s[0] += wa.x * c[t]; s[1] += wa.y * c[t]; s[2] += wa.z * c[t]; s[3] += wa.w * c[t];
        s[4] += wb.x * c[t]; s[5] += wb.y * c[t]; s[6] += wb.z * c[t]; s[7] += wb.w * c[t];
    }
#pragma unroll
    for (int off = 1; off < 64; off <<= 1)
#pragma unroll
        for (int j = 0; j < 8; ++j)
            s[j] += __shfl_xor(s[j], off, 64);
    if (lane == 0) {
        float* o = zwT + (long)Q * 8;
        *(float4*)o = make_float4(s[0], s[1], s[2], s[3]);
        *(float4*)(o + 4) = make_float4(s[4], s[5], s[6], s[7]);
    }
}

// ---------------- border_zero ----------------
__global__ __launch_bounds__(256) void border_zero_kernel(u16* __restrict__ ftb)
{
    int gid = blockIdx.x * 256 + threadIdx.x;   // 8 * 260 * 32 uint4
    if (gid >= 8 * 260 * 32) return;
    int n = gid / (260 * 32);
    int rem = gid - n * (260 * 32);
    int r = rem >> 5;
    int i = rem & 31;
    int h, w;
    if (r < 66)       { h = 0;  w = r; }
    else if (r < 132) { h = 65; w = r - 66; }
    else { int j = r - 132; h = 1 + (j >> 1); w = (j & 1) * 65; }
    long prow = (long)h * 66 + w;
    uint4* dst = (uint4*)(ftb + (long)n * 4356 * 256 + prow * 256) + i;
    *dst = make_uint4(0, 0, 0, 0);
}

// ---------------- carafe_fuse_blend: no z-staging (z is L2-resident) ----------------
// 32 px / block, ~17 KB LDS -> 7-8 blocks/CU. OOB taps handled by m9[k]=0
// (algebraically == zero-padded patch). Tap pointers precomputed, loops fully
// unrolled so zp[] stays in registers (rule #20).
__global__ __launch_bounds__(256) void carafe_fuse_blend_kernel(
    const float* __restrict__ i1g, const u16* __restrict__ zbfT,
    const float* __restrict__ zwT, const float* __restrict__ maskb,
    const float* __restrict__ bnp,          // 512..519 c2, 768.. b_up
    const float* __restrict__ w_l1, const float* __restrict__ bn_l1,
    const float* __restrict__ bn_l2, const float* __restrict__ w_wl,
    const float* __restrict__ b_wl, u16* __restrict__ dst)
{
    __shared__ float lw0s[32];
    __shared__ __align__(16) unsigned char uscr[32 * 264 * 2];  // 16.5 KB union
    float* red = (float*)uscr;                      // [8][32][8] = 8 KB
    u16* lds2 = (u16*)uscr;                         // [32][264]
    const int n = blockIdx.y;
    const int h = blockIdx.x >> 1;
    const int w0 = (blockIdx.x & 1) << 5;
    const int hq = h >> 1;
    const int tid = threadIdx.x;

    const int w = tid & 31;
    const int chunk = tid >> 5;
    const float* i1 = i1g + (long)n * 256 * 4096 + (h << 6) + w0 + w;
    {   // pass1: v1 partials (i1 HBM read #1)
        float s1[8] = {};
        for (int ci = chunk * 32; ci < chunk * 32 + 32; ++ci) {
            float x1 = i1[(long)ci * 4096];
#pragma unroll
            for (int j = 0; j < 8; ++j) s1[j] += w_l1[j * 256 + ci] * x1;
        }
#pragma unroll
        for (int j = 0; j < 8; ++j) red[(chunk * 32 + w) * 8 + j] = s1[j];
    }
    __syncthreads();
    {   // reduce over 8 chunks: 256 cells
        int px = tid >> 3, j = tid & 7;
        float s = 0.f;
#pragma unroll
        for (int o = 0; o < 8; ++o) s += red[(o * 32 + px) * 8 + j];
        red[px * 8 + j] = s;
    }
    __syncthreads();
    if (tid < 32) {     // lw0 per pixel (mask/zw from L2)
        const int wp = w0 + tid;
        const int wq = wp >> 1;
        const int q = ((h & 1) << 1) | (wp & 1);
        const float* mrow = maskb + ((long)n * 1024 + hq * 32 + wq) * 36;
        float v[16];
#pragma unroll
        for (int j = 0; j < 8; ++j) v[j] = red[tid * 8 + j];
#pragma unroll
        for (int j = 0; j < 8; ++j) v[8 + j] = bnp[512 + j];   // c2
#pragma unroll
        for (int k = 0; k < 9; ++k) {
            int dh = k / 3 - 1, dw = k - (k / 3) * 3 - 1;
            int gr = hq + dh, gc = wq + dw;
            bool ok = (gr >= 0 && gr < 32 && gc >= 0 && gc < 32);
            float mk = ok ? mrow[k * 4 + q] : 0.f;
            const float* zp = zwT + ((long)n * 1024 +
                                     (ok ? gr * 32 + gc : hq * 32 + wq)) * 8;
            float4 za = *(const float4*)zp;
            float4 zb = *(const float4*)(zp + 4);
            v[8]  += mk * za.x; v[9]  += mk * za.y; v[10] += mk * za.z; v[11] += mk * za.w;
            v[12] += mk * zb.x; v[13] += mk * zb.y; v[14] += mk * zb.z; v[15] += mk * zb.w;
        }
        float z0 = b_wl[0], z1 = b_wl[1];
#pragma unroll
        for (int j = 0; j < 8; ++j) {
            float g = bn_l1[j], b = bn_l1[8 + j], m = bn_l1[16 + j], va = bn_l1[24 + j];
            float y = (v[j] - m) * (g * rsqrtf(va + EPS)) + b;
            float sv = y / (1.f + expf(-y));
            z0 += w_wl[j] * sv;
            z1 += w_wl[16 + j] * sv;
            g = bn_l2[j]; b = bn_l2[8 + j]; m = bn_l2[16 + j]; va = bn_l2[24 + j];
            y = (v[8 + j] - m) * (g * rsqrtf(va + EPS)) + b;
            sv = y / (1.f + expf(-y));
            z0 += w_wl[8 + j] * sv;
            z1 += w_wl[24 + j] * sv;
        }
        lw0s[tid] = 1.f / (1.f + expf(z1 - z0));
    }
    __syncthreads();
    {   // pass2: u = CARAFE(z from L2)+b_up ; blend (i1 L2-hot) ; bf16 into lds2
        const float lw = lw0s[w], lw1 = 1.f - lw;
        const int wp = w0 + w;
        const int wq = wp >> 1;
        const int q = ((h & 1) << 1) | (wp & 1);
        const float* mrow = maskb + ((long)n * 1024 + hq * 32 + wq) * 36;
        float m9[9];
        const u16* zp[9];
#pragma unroll
        for (int k = 0; k < 9; ++k) {
            int dh = k / 3 - 1, dw = k - (k / 3) * 3 - 1;
            int gr = hq + dh, gc = wq + dw;
            bool ok = (gr >= 0 && gr < 32 && gc >= 0 && gc < 32);
            m9[k] = ok ? mrow[k * 4 + q] : 0.f;
            zp[k] = zbfT + ((long)n * 1024 +
                            (ok ? gr * 32 + gc : hq * 32 + wq)) * 256;
        }
        for (int ci = chunk * 32; ci < chunk * 32 + 32; ci += 8) {
            float uu[8];
            {
                float4 ba = *(const float4*)(bnp + 768 + ci);
                float4 bb = *(const float4*)(bnp + 768 + ci + 4);
                uu[0] = ba.x; uu[1] = ba.y; uu[2] = ba.z; uu[3] = ba.w;
                uu[4] = bb.x; uu[5] = bb.y; uu[6] = bb.z; uu[7] = bb.w;
            }
#pragma unroll
            for (int k = 0; k < 9; ++k) {
                uint4 vz = *(const uint4*)(zp[k] + ci);
                float mk = m9[k];
                uu[0] += mk * bf2f((u16)(vz.x & 0xffff));
                uu[1] += mk * bf2f((u16)(vz.x >> 16));
                uu[2] += mk * bf2f((u16)(vz.y & 0xffff));
                uu[3] += mk * bf2f((u16)(vz.y >> 16));
                uu[4] += mk * bf2f((u16)(vz.z & 0xffff));
                uu[5] += mk * bf2f((u16)(vz.z >> 16));
                uu[6] += mk * bf2f((u16)(vz.w & 0xffff));
                uu[7] += mk * bf2f((u16)(vz.w >> 16));
            }
            unsigned o0 = (unsigned)f2bf(i1[(long)ci * 4096] * lw + uu[0] * lw1)
                        | ((unsigned)f2bf(i1[(long)(ci + 1) * 4096] * lw + uu[1] * lw1) << 16);
            unsigned o1 = (unsigned)f2bf(i1[(long)(ci + 2) * 4096] * lw + uu[2] * lw1)
                        | ((unsigned)f2bf(i1[(long)(ci + 3) * 4096] * lw + uu[3] * lw1) << 16);
            unsigned o2 = (unsigned)f2bf(i1[(long)(ci + 4) * 4096] * lw + uu[4] * lw1)
                        | ((unsigned)f2bf(i1[(long)(ci + 5) * 4096] * lw + uu[5] * lw1) << 16);
            unsigned o3 = (unsigned)f2bf(i1[(long)(ci + 6) * 4096] * lw + uu[6] * lw1)
                        | ((unsigned)f2bf(i1[(long)(ci + 7) * 4096] * lw + uu[7] * lw1) << 16);
            *(uint4*)(lds2 + w * 264 + ci) = make_uint4(o0, o1, o2, o3);
        }
    }
    __syncthreads();
    {   // transposed padded write
        const int px = tid >> 3, qd = tid & 7;
        const int pg = (h << 6) + w0 + px;
        long prow = (long)((pg >> 6) + 1) * 66 + (pg & 63) + 1;
        u16* drow = dst + (long)n * 4356 * 256 + prow * 256;
        const u16* lrow = lds2 + px * 264;
#pragma unroll
        for (int j = 0; j < 16; ++j) {
            int off = j * 16 + qd * 2;
            *(unsigned*)(drow + off) = *(const unsigned*)(lrow + off);
        }
    }
}

// ---------------- K7: m97 GEMM — post-barrier 2-deep A staging (round-15 proven) ----------------
template<int KCC, int NT, bool PADDED>
__global__ __launch_bounds__(256, 2) void gemm_m97_kernel(
    const u16* __restrict__ A,      // [NT][256][KCC] bf16
    const u16* __restrict__ B,      // per image [rows][KCC] bf16
    const float* __restrict__ scale, const float* __restrict__ shift,
    float* __restrict__ C, long strideB, long strideC, int silu)
{
    constexpr int RROWS = PADDED ? 264 : 128;
    constexpr int BUNITS = RROWS * 4;
    constexpr int NKX = KCC / 32;
    constexpr int S = NKX * NT;
    __shared__ __align__(16) u16 lsA[3][128 * 32];
    __shared__ __align__(16) u16 lsB[2][RROWS * 32];
    const int n = blockIdx.z;
    const u16* Bn = B + (long)n * strideB;
    float* Cn = C + (long)n * strideC;
    const int tid = threadIdx.x;
    const int lane = tid & 63;
    const int wid = tid >> 6;
    const int mw = wid >> 1, nw = wid & 1;
    const int lr = lane & 15, lk = lane >> 4;
    const int rowBase = blockIdx.y * 128;
    const int colBase = blockIdx.x * 128;
    const int g0 = PADDED ? (colBase >> 6) * 66 : colBase;

    STAGE_B(lsB[0], 0);
    STAGE_A(lsA[0], 0, 0);
    STAGE_A(lsA[1], (NT > 1 ? 1 : 0), (NT > 1 ? 0 : 1));

    const int aswz = (lk ^ ((lr >> 1) & 3)) << 3;
    int aoff[4];
#pragma unroll
    for (int mf = 0; mf < 4; ++mf)
        aoff[mf] = (mw * 64 + mf * 16 + lr) * 32 + aswz;

    f32x4 acc[4][4] = {};
    for (int kx = 0; kx < NKX; ++kx) {
        const u16* lb = lsB[kx & 1];
#pragma unroll
        for (int t = 0; t < NT; ++t) {
            const int s = kx * NT + t;
            if (s == S - 1) { VMCNT(0); } else { VMCNT(2); }
            __builtin_amdgcn_s_barrier();
            asm volatile("" ::: "memory");
            if (s + 2 < S) {
                const int s2 = s + 2;
                const int kx2 = s2 / NT;
                const int t2 = s2 - kx2 * NT;
                STAGE_A(lsA[s2 % 3], t2, kx2);
            }
            if (t == 0 && kx + 1 < NKX) STAGE_B(lsB[(kx + 1) & 1], kx + 1);

            const u16* la = lsA[s % 3];
            bf16x8 af[4], bfr[4];
#pragma unroll
            for (int mf = 0; mf < 4; ++mf)
                af[mf] = *(const bf16x8*)(la + aoff[mf]);
            int rb;
            if (PADDED) {
                int dh = t / 3 - 1, dw = t - (t / 3) * 3 - 1;
                rb = (nw + dh + 1) * 66 + dw + 1 + lr;
            } else {
                rb = nw * 64 + lr;
            }
            const int bswz = (lk ^ ((rb >> 1) & 3)) << 3;
#pragma unroll
            for (int nf = 0; nf < 4; ++nf)
                bfr[nf] = *(const bf16x8*)(lb + (rb + nf * 16) * 32 + bswz);
#pragma unroll
            for (int mf = 0; mf < 4; ++mf)
#pragma unroll
                for (int nf = 0; nf < 4; ++nf)
                    acc[mf][nf] = __builtin_amdgcn_mfma_f32_16x16x32_bf16(
                        af[mf], bfr[nf], acc[mf][nf], 0, 0, 0);
        }
    }

#pragma unroll
    for (int mf = 0; mf < 4; ++mf) {
#pragma unroll
        for (int reg = 0; reg < 4; ++reg) {
            int co = rowBase + mw * 64 + mf * 16 + lk * 4 + reg;
            float sc = scale[co], sh = shift[co];
#pragma unroll
            for (int nf = 0; nf < 4; ++nf) {
                int col = colBase + nw * 64 + nf * 16 + lr;
                float y = acc[mf][nf][reg] * sc + sh;
                if (silu) y = y / (1.f + expf(-y));
                Cn[(long)co * 4096 + col] = y;
            }
        }
    }
}

// ---------------- prep kernels ----------------
__global__ __launch_bounds__(256) void prep_w_kernel(
    const float* __restrict__ w_conv, const float* __restrict__ w_up,
    const float* __restrict__ w_enc, const float* __restrict__ w_down,
    u16* __restrict__ wT, u16* __restrict__ wupT, u16* __restrict__ wencT,
    u16* __restrict__ wdT)
{
    int gid = blockIdx.x * 256 + threadIdx.x;
    if (gid < 589824) {             // wT[t][co][ci] = w_conv[co][ci][t]
        int t = gid >> 16;
        int co = (gid >> 8) & 255;
        int ci = gid & 255;
        wT[gid] = f2bf(w_conv[(co * 256 + ci) * 9 + t]);
    }
    if (gid < 131072) wupT[gid] = f2bf(w_up[gid]);
    if (gid < 73728) {              // wencT[t][co<64][ci] (zeros co>=36)
        int t = gid >> 13;
        int co = (gid >> 7) & 63;
        int ci = gid & 127;
        wencT[gid] = (co < 36) ? f2bf(w_enc[(co * 128 + ci) * 9 + t]) : (u16)0;
    }
    if (gid < 65536) wdT[gid] = f2bf(w_down[gid]);
}

__global__ void prep_bn_kernel(const float* __restrict__ bn_conv,
                               const float* __restrict__ b_up,
                               const float* __restrict__ w_l2,
                               float* __restrict__ bnp, float* __restrict__ wl2T)
{
    int i = threadIdx.x;            // 256
    float g = bn_conv[i], b = bn_conv[256 + i], m = bn_conv[512 + i], v = bn_conv[768 + i];
    float sc = g * rsqrtf(v + EPS);
    bnp[i] = sc;
    bnp[256 + i] = b - m * sc;
    bnp[768 + i] = b_up[i];
    if (i < 8) {                    // c2[j] = w_l2[j] . b_up
        float s = 0.f;
        for (int co = 0; co < 256; ++co) s += w_l2[i * 256 + co] * b_up[co];
        bnp[512 + i] = s;
    }
#pragma unroll
    for (int j = 0; j < 8; ++j)     // wl2T[co][j]
        wl2T[i * 8 + j] = w_l2[j * 256 + i];
}

extern "C" void kernel_launch(void* const* d_in, const int* in_sizes, int n_in,
                              void* d_out, int out_size, void* d_ws, size_t ws_size,
                              hipStream_t stream)
{
    const float* input1 = (const float*)d_in[0];
    const float* input2 = (const float*)d_in[1];
    const float* w_down = (const float*)d_in[2];
    const float* b_down = (const float*)d_in[3];
    const float* w_enc  = (const float*)d_in[4];
    const float* b_enc  = (const float*)d_in[5];
    const float* w_up   = (const float*)d_in[6];
    const float* b_up   = (const float*)d_in[7];
    const float* w_l1   = (const float*)d_in[8];
    const float* bn_l1  = (const float*)d_in[9];
    const float* w_l2   = (const float*)d_in[10];
    const float* bn_l2  = (const float*)d_in[11];
    const float* w_wl   = (const float*)d_in[12];
    const float* b_wl   = (const float*)d_in[13];
    const float* w_conv = (const float*)d_in[14];
    const float* bn_conv= (const float*)d_in[15];
    float* out = (float*)d_out;

    // workspace layout (float units). ~38 MB total.
    float* ws     = (float*)d_ws;
    float* ktTf   = ws;                      //   591,872 f : ktT bf16 [n][1156][128]
    float* wencTf = ktTf + 591872;           //    36,864 f
    float* kt2    = wencTf + 36864;          //   294,912 f
    float* maskb  = kt2 + 294912;            //   294,912 f
    float* in2Tf  = maskb + 294912;          // 2,097,152 f : in2T bf16 [n][1024][512]
    float* zbfTf  = in2Tf + 2097152;         // 1,048,576 f : zbfT bf16 [n][1024][256]
    float* zwT    = zbfTf + 1048576;         //    65,536 f : [n][1024][8] fp32
    float* ftbf   = zwT + 65536;             // 4,460,544 f : fusedT bf16 [n][4356][256]
    float* wTf    = ftbf + 4460544;          //   294,912 f
    float* wupTf  = wTf + 294912;            //    65,536 f
    float* wdTf   = wupTf + 65536;           //    32,768 f
    float* wl2T   = wdTf + 32768;            //     2,048 f
    float* bnp    = wl2T + 2048;             //     1,024 f
    u16* ktT      = (u16*)ktTf;
    u16* wencT    = (u16*)wencTf;
    u16* in2T     = (u16*)in2Tf;
    u16* zbfT     = (u16*)zbfTf;
    u16* ftb      = (u16*)ftbf;
    u16* wT       = (u16*)wTf;
    u16* wupT     = (u16*)wupTf;
    u16* wdT      = (u16*)wdTf;

    // prep (independent)
    prep_w_kernel<<<dim3(2304), 256, 0, stream>>>(w_conv, w_up, w_enc, w_down,
                                                  wT, wupT, wencT, wdT);
    prep_bn_kernel<<<dim3(1), 256, 0, stream>>>(bn_conv, b_up, w_l2, bnp, wl2T);
    border_zero_kernel<<<dim3(260), 256, 0, stream>>>(ftb);
    hipMemsetAsync(ktT, 0, 8L * 1156 * 128 * 2, stream);

    // in2T (feeds lowres_gemm)
    in2t_kernel<<<dim3(16, 8), 256, 0, stream>>>(input2, in2T);

    // merged lowres GEMM: zbfT (y<2) + ktT (y==2)
    lowres_gemm_kernel<<<dim3(8, 3, 8), 256, 0, stream>>>(
        wupT, wdT, in2T, b_down, zbfT, ktT);

    // mask pipeline
    enc_mfma_kernel<<<dim3(64, 8), 64, 0, stream>>>(wencT, ktT, b_enc, kt2);
    mask_softmax_kernel<<<dim3(128), 256, 0, stream>>>(kt2, maskb);

    // zw
    zw_kernel<<<dim3(2048), 256, 0, stream>>>(zbfT, wl2T, zwT);

    // merged level-attention + CARAFE + blend -> fusedT (z from L2, no staging)
    carafe_fuse_blend_kernel<<<dim3(128, 8), 256, 0, stream>>>(
        input1, zbfT, zwT, maskb, bnp, w_l1, bn_l1, bn_l2, w_wl, b_wl, ftb);

    // K7: final conv + BN + SiLU
    gemm_m97_kernel<256, 9, true><<<dim3(32, 2, 8), 256, 0, stream>>>(
        wT, ftb, bnp, bnp + 256, out, 4356L * 256, 256L * 4096, 1);
}

// Round 20
// 140.591 us; speedup vs baseline: 1.2477x; 1.0687x over previous
//
#include <hip/hip_runtime.h>
#include <math.h>

// ASFF_2: N=8, C1=256, C2=512, H=64, W=64, low-res 32x32.
// CARAFE-commutation: u = CARAFE(z)+b_up with z = w_up@in2 (low-res GEMM);
// v2 = CARAFE(zw)+c2 with zw = w_l2@z, c2 = w_l2@b_up.
//  in2t: input2 -> in2T bf16 [n][1024][512]
//  lowres_gemm (merged): y<2 -> zbfT = bf16(w_up @ in2T); y==2 -> ktT
//  enc_softmax (merged): 9-tap enc MFMA + in-register softmax -> maskb
//  zw: zwT[n][1024][8] = w_l2 @ z
//  carafe_fuse_blend: v1 in-block -> lw0 ; u=CARAFE(z)+b_up ; blend -> fusedT
//  K7: m97 GEMM, post-barrier 2-phase-deep A staging (LDS-read-issue-limited
//      structure ceiling; 708 TF effective).

#define EPS 1e-5f
typedef unsigned short u16;
typedef __attribute__((ext_vector_type(8))) __bf16 bf16x8;
typedef __attribute__((ext_vector_type(4))) float f32x4;

#define VMCNT(N) asm volatile("s_waitcnt vmcnt(" #N ")" ::: "memory")

__device__ inline u16 f2bf(float x) {
    union { float f; unsigned u; } v; v.f = x;
    unsigned r = v.u + 0x7FFF + ((v.u >> 16) & 1);
    return (u16)(r >> 16);
}
__device__ inline float bf2f(u16 x) {
    union { unsigned u; float f; } v; v.u = (unsigned)x << 16; return v.f;
}

// ---------------- in2t: transpose-cast input2 [512][1024] -> in2T bf16 [q][512] ----------------
__global__ __launch_bounds__(256) void in2t_kernel(
    const float* __restrict__ src0, u16* __restrict__ dst)
{
    constexpr int CP = 516;
    __shared__ u16 lds[64 * CP];
    const int n = blockIdx.y;
    const int p0 = blockIdx.x * 64;
    const int tid = threadIdx.x;
    {
        const int px = tid & 63;
        const float* src = src0 + (long)n * 512 * 1024 + p0 + px;
        for (int ci = tid >> 6; ci < 512; ci += 4)
            lds[px * CP + ci] = f2bf(src[(long)ci * 1024]);
    }
    __syncthreads();
    const int px = tid >> 2;
    const int qd = tid & 3;
    u16* drow = dst + ((long)n * 1024 + p0 + px) * 512;
    const u16* lrow = lds + px * CP;
#pragma unroll
    for (int j = 0; j < 16; ++j) {
        int off = j * 32 + qd * 8;
        *(uint4*)(drow + off) = *(const uint4*)(lrow + off);
    }
}

// ---------------- staging macros ----------------
#define STAGE_A(dstp, t, kx)                                                         \
    {                                                                                \
        const u16* Abase = A + ((long)(t) * 256 + rowBase) * KCC + (kx) * 32;        \
        _Pragma("unroll")                                                            \
        for (int ii = 0; ii < 2; ++ii) {                                             \
            int f = ii * 256 + tid;                                                  \
            int r = f >> 2, uu = f & 3;                                              \
            __builtin_amdgcn_global_load_lds(                                        \
                (const __attribute__((address_space(1))) void*)                      \
                    (Abase + (long)r * KCC + ((uu ^ ((r >> 1) & 3)) << 3)),          \
                (__attribute__((address_space(3))) void*)((dstp) + f * 8),           \
                16, 0, 0);                                                           \
        }                                                                            \
    }

#define STAGE_B(dstp, kx)                                                            \
    {                                                                                \
        const u16* Bbase = Bn + (long)g0 * KCC + (kx) * 32;                          \
        for (int f = tid; f < BUNITS; f += 256) {                                    \
            int r = f >> 2, uu = f & 3;                                              \
            __builtin_amdgcn_global_load_lds(                                        \
                (const __attribute__((address_space(1))) void*)                      \
                    (Bbase + (long)r * KCC + ((uu ^ ((r >> 1) & 3)) << 3)),          \
                (__attribute__((address_space(3))) void*)((dstp) + f * 8),           \
                16, 0, 0);                                                           \
        }                                                                            \
    }

// ---------------- lowres_gemm (merged zgemm + down_mfma) ----------------
__global__ __launch_bounds__(256, 2) void lowres_gemm_kernel(
    const u16* __restrict__ Aup,    // wupT [256][512]
    const u16* __restrict__ Adn,    // wdT  [128][512]
    const u16* __restrict__ B,      // in2T [n][1024][512]
    const float* __restrict__ bias, // b_down
    u16* __restrict__ Z,            // zbfT [n][1024][256]
    u16* __restrict__ ktT)          // [n][1156][128] padded
{
    constexpr int KCC = 512;
    constexpr int BUNITS = 512;
    __shared__ __align__(16) u16 lsA[3][128 * 32];
    __shared__ __align__(16) u16 lsB[3][128 * 32];
    const int n = blockIdx.z;
    const u16* Bn = B + (long)n * 1024 * 512;
    const int tid = threadIdx.x;
    const int lane = tid & 63;
    const int wid = tid >> 6;
    const int mw = wid >> 1, nw = wid & 1;
    const int lr = lane & 15, lk = lane >> 4;
    const int ybr = blockIdx.y;
    const u16* A = (ybr < 2) ? Aup : Adn;
    const int rowBase = (ybr < 2) ? ybr * 128 : 0;
    const int colBase = blockIdx.x * 128;
    const int g0 = colBase;

    STAGE_A(lsA[0], 0, 0); STAGE_B(lsB[0], 0);
    STAGE_A(lsA[1], 0, 1); STAGE_B(lsB[1], 1);

    const int aswz = (lk ^ ((lr >> 1) & 3)) << 3;
    int aoff[4];
#pragma unroll
    for (int mf = 0; mf < 4; ++mf)
        aoff[mf] = (mw * 64 + mf * 16 + lr) * 32 + aswz;

    f32x4 acc[4][4] = {};
    for (int kx = 0; kx < 16; ++kx) {
        if (kx == 15) { VMCNT(0); } else { VMCNT(4); }
        __builtin_amdgcn_s_barrier();
        asm volatile("" ::: "memory");
        if (kx + 2 < 16) {
            STAGE_A(lsA[(kx + 2) % 3], 0, kx + 2);
            STAGE_B(lsB[(kx + 2) % 3], kx + 2);
        }
        const u16* la = lsA[kx % 3];
        const u16* lb = lsB[kx % 3];
        bf16x8 af[4], bfr[4];
#pragma unroll
        for (int mf = 0; mf < 4; ++mf)
            af[mf] = *(const bf16x8*)(la + aoff[mf]);
        const int rb = nw * 64 + lr;
        const int bswz = (lk ^ ((rb >> 1) & 3)) << 3;
#pragma unroll
        for (int nf = 0; nf < 4; ++nf)
            bfr[nf] = *(const bf16x8*)(lb + (rb + nf * 16) * 32 + bswz);
#pragma unroll
        for (int mf = 0; mf < 4; ++mf)
#pragma unroll
            for (int nf = 0; nf < 4; ++nf)
                acc[mf][nf] = __builtin_amdgcn_mfma_f32_16x16x32_bf16(
                    af[mf], bfr[nf], acc[mf][nf], 0, 0, 0);
    }

    if (ybr < 2) {
        u16* Zn = Z + (long)n * 1024 * 256;
#pragma unroll
        for (int mf = 0; mf < 4; ++mf) {
            const int co0 = rowBase + mw * 64 + mf * 16 + lk * 4;
#pragma unroll
            for (int nf = 0; nf < 4; ++nf) {
                const int col = colBase + nw * 64 + nf * 16 + lr;
                unsigned lo = (unsigned)f2bf(acc[mf][nf][0]) |
                              ((unsigned)f2bf(acc[mf][nf][1]) << 16);
                unsigned hi = (unsigned)f2bf(acc[mf][nf][2]) |
                              ((unsigned)f2bf(acc[mf][nf][3]) << 16);
                *(uint2*)(Zn + (long)col * 256 + co0) = make_uint2(lo, hi);
            }
        }
    } else {
        u16* Kn = ktT + (long)n * 1156 * 128;
#pragma unroll
        for (int mf = 0; mf < 4; ++mf) {
            const int co0 = mw * 64 + mf * 16 + lk * 4;     // 0..124
            float b0 = bias[co0], b1 = bias[co0 + 1], b2 = bias[co0 + 2], b3 = bias[co0 + 3];
#pragma unroll
            for (int nf = 0; nf < 4; ++nf) {
                const int col = colBase + nw * 64 + nf * 16 + lr;   // 0..1023
                const int pr = ((col >> 5) + 1) * 34 + (col & 31) + 1;
                unsigned lo = (unsigned)f2bf(acc[mf][nf][0] + b0) |
                              ((unsigned)f2bf(acc[mf][nf][1] + b1) << 16);
                unsigned hi = (unsigned)f2bf(acc[mf][nf][2] + b2) |
                              ((unsigned)f2bf(acc[mf][nf][3] + b3) << 16);
                *(uint2*)(Kn + (long)pr * 128 + co0) = make_uint2(lo, hi);
            }
        }
    }
}

// ---------------- enc_softmax: 9-tap enc MFMA + in-register softmax -> maskb ----------------
// C/D layout: co = mf*16 + lk*4 + reg, p = lr. For fixed (p, q=reg): the 9
// softmax inputs k=mf*4+lk live across lanes lk=0..3 (shfl_xor 16/32 reduce);
// k=8 only at lk==0 (mf==2). Writes maskb[p][36] directly (kt2 eliminated).
__global__ __launch_bounds__(64) void enc_softmax_kernel(
    const u16* __restrict__ A, const u16* __restrict__ B,
    const float* __restrict__ bias, float* __restrict__ mask)
{
    const int n = blockIdx.y;
    const int lane = threadIdx.x;
    const int lr = lane & 15, lk = lane >> 4;
    const int p = blockIdx.x * 16 + lr;
    const int pr = ((p >> 5) + 1) * 34 + (p & 31) + 1;
    const u16* Bn = B + (long)n * 1156 * 128;
    const int bOff = pr * 128 + lk * 8;
    f32x4 acc[3] = {};
    for (int t = 0; t < 9; ++t) {
        const u16* At = A + t * 8192;
        const int btap = ((t / 3 - 1) * 34 + (t % 3 - 1)) * 128;
#pragma unroll
        for (int k0 = 0; k0 < 128; k0 += 32) {
            bf16x8 bf = *(const bf16x8*)(Bn + bOff + btap + k0);
#pragma unroll
            for (int mf = 0; mf < 3; ++mf) {
                bf16x8 af = *(const bf16x8*)(At + (mf * 16 + lr) * 128 + lk * 8 + k0);
                acc[mf] = __builtin_amdgcn_mfma_f32_16x16x32_bf16(af, bf, acc[mf], 0, 0, 0);
            }
        }
    }
    float* mp = mask + ((long)n * 1024 + p) * 36;
#pragma unroll
    for (int q = 0; q < 4; ++q) {
        float v0 = acc[0][q] + bias[lk * 4 + q];            // k = lk
        float v1 = acc[1][q] + bias[16 + lk * 4 + q];       // k = 4 + lk
        float v2 = (lk == 0) ? (acc[2][q] + bias[32 + q]) : -1e30f;   // k = 8
        float m = fmaxf(fmaxf(v0, v1), v2);
        m = fmaxf(m, __shfl_xor(m, 16, 64));
        m = fmaxf(m, __shfl_xor(m, 32, 64));
        float e0 = expf(v0 - m);
        float e1 = expf(v1 - m);
        float e2 = (lk == 0) ? expf(v2 - m) : 0.f;
        float s = e0 + e1 + e2;
        s += __shfl_xor(s, 16, 64);
        s += __shfl_xor(s, 32, 64);
        float inv = 1.f / s;
        mp[lk * 4 + q] = e0 * inv;
        mp[16 + lk * 4 + q] = e1 * inv;
        if (lk == 0) mp[32 + q] = e2 * inv;
    }
}

// ---------------- zw: one wave per low-res pixel, butterfly reduce ----------------
__global__ __launch_bounds__(256) void zw_kernel(
    const u16* __restrict__ zbfT, const float* __restrict__ wl2T,
    float* __restrict__ zwT)
{
    const int Q = (blockIdx.x * 256 + threadIdx.x) >> 6;   // 0..8191
    const int lane = threadIdx.x & 63;
    const int ci0 = lane * 4;
    uint2 v = *(const uint2*)(zbfT + (long)Q * 256 + ci0);
    float c[4] = { bf2f((u16)(v.x & 0xffff)), bf2f((u16)(v.x >> 16)),
                   bf2f((u16)(v.y & 0xffff)), bf2f((u16)(v.y >> 16)) };
    float s[8] = {};
#pragma unroll
    for (int t = 0; t < 4; ++t) {
        const float* wr = wl2T + (ci0 + t) * 8;
        float4 wa = *(const float4*)wr;
        float4 wb = *(const float4*)(wr + 4);
        s[0] += wa.x * c[t]; s[1] += wa.y * c[t]; s[2] += wa.z * c[t]; s[3] += wa.w * c[t];
        s[4] += wb.x * c[t]; s[5] += wb.y * c[t]; s[6] += wb.z * c[t]; s[7] += wb.w * c[t];
    }
#pragma unroll
    for (int off = 1; off < 64; off <<= 1)
#pragma unroll
        for (int j = 0; j < 8; ++j)
            s[j] += __shfl_xor(s[j], off, 64);
    if (lane == 0) {
        float* o = zwT + (long)Q * 8;
        *(float4*)o = make_float4(s[0], s[1], s[2], s[3]);
        *(float4*)(o + 4) = make_float4(s[4], s[5], s[6], s[7]);
    }
}

// ---------------- border_zero: fusedT 66x66 pad ring + ktT 34x34 pad ring ----------------
__global__ __launch_bounds__(256) void border_zero_kernel(
    u16* __restrict__ ftb, u16* __restrict__ ktT)
{
    int gid = blockIdx.x * 256 + threadIdx.x;
    if (gid < 8 * 260 * 32) {                   // fusedT ring: 8 img x 260 rows x 32 uint4
        int n = gid / (260 * 32);
        int rem = gid - n * (260 * 32);
        int r = rem >> 5;
        int i = rem & 31;
        int h, w;
        if (r < 66)       { h = 0;  w = r; }
        else if (r < 132) { h = 65; w = r - 66; }
        else { int j = r - 132; h = 1 + (j >> 1); w = (j & 1) * 65; }
        long prow = (long)h * 66 + w;
        uint4* dst = (uint4*)(ftb + (long)n * 4356 * 256 + prow * 256) + i;
        *dst = make_uint4(0, 0, 0, 0);
        return;
    }
    int g2 = gid - 8 * 260 * 32;                // ktT ring: 8 img x 132 rows x 16 uint4
    if (g2 >= 8 * 132 * 16) return;
    int n = g2 / (132 * 16);
    int rem = g2 - n * (132 * 16);
    int r = rem >> 4;
    int i = rem & 15;
    int h, w;
    if (r < 34)      { h = 0;  w = r; }
    else if (r < 68) { h = 33; w = r - 34; }
    else { int j = r - 68; h = 1 + (j >> 1); w = (j & 1) * 33; }
    long prow = (long)h * 34 + w;
    uint4* dst = (uint4*)(ktT + (long)n * 1156 * 128 + prow * 128) + i;
    *dst = make_uint4(0, 0, 0, 0);
}

// ---------------- carafe_fuse_blend: no z-staging (z is L2-resident) ----------------
__global__ __launch_bounds__(256) void carafe_fuse_blend_kernel(
    const float* __restrict__ i1g, const u16* __restrict__ zbfT,
    const float* __restrict__ zwT, const float* __restrict__ maskb,
    const float* __restrict__ bnp,          // 512..519 c2, 768.. b_up
    const float* __restrict__ w_l1, const float* __restrict__ bn_l1,
    const float* __restrict__ bn_l2, const float* __restrict__ w_wl,
    const float* __restrict__ b_wl, u16* __restrict__ dst)
{
    __shared__ float lw0s[32];
    __shared__ __align__(16) unsigned char uscr[32 * 264 * 2];  // 16.5 KB union
    float* red = (float*)uscr;                      // [8][32][8] = 8 KB
    u16* lds2 = (u16*)uscr;                         // [32][264]
    const int n = blockIdx.y;
    const int h = blockIdx.x >> 1;
    const int w0 = (blockIdx.x & 1) << 5;
    const int hq = h >> 1;
    const int tid = threadIdx.x;

    const int w = tid & 31;
    const int chunk = tid >> 5;
    const float* i1 = i1g + (long)n * 256 * 4096 + (h << 6) + w0 + w;
    {   // pass1: v1 partials (i1 HBM read #1)
        float s1[8] = {};
        for (int ci = chunk * 32; ci < chunk * 32 + 32; ++ci) {
            float x1 = i1[(long)ci * 4096];
#pragma unroll
            for (int j = 0; j < 8; ++j) s1[j] += w_l1[j * 256 + ci] * x1;
        }
#pragma unroll
        for (int j = 0; j < 8; ++j) red[(chunk * 32 + w) * 8 + j] = s1[j];
    }
    __syncthreads();
    {   // reduce over 8 chunks: 256 cells
        int px = tid >> 3, j = tid & 7;
        float s = 0.f;
#pragma unroll
        for (int o = 0; o < 8; ++o) s += red[(o * 32 + px) * 8 + j];
        red[px * 8 + j] = s;
    }
    __syncthreads();
    if (tid < 32) {     // lw0 per pixel (mask/zw from L2)
        const int wp = w0 + tid;
        const int wq = wp >> 1;
        const int q = ((h & 1) << 1) | (wp & 1);
        const float* mrow = maskb + ((long)n * 1024 + hq * 32 + wq) * 36;
        float v[16];
#pragma unroll
        for (int j = 0; j < 8; ++j) v[j] = red[tid * 8 + j];
#pragma unroll
        for (int j = 0; j < 8; ++j) v[8 + j] = bnp[512 + j];   // c2
#pragma unroll
        for (int k = 0; k < 9; ++k) {
            int dh = k / 3 - 1, dw = k - (k / 3) * 3 - 1;
            int gr = hq + dh, gc = wq + dw;
            bool ok = (gr >= 0 && gr < 32 && gc >= 0 && gc < 32);
            float mk = ok ? mrow[k * 4 + q] : 0.f;
            const float* zp = zwT + ((long)n * 1024 +
                                     (ok ? gr * 32 + gc : hq * 32 + wq)) * 8;
            float4 za = *(const float4*)zp;
            float4 zb = *(const float4*)(zp + 4);
            v[8]  += mk * za.x; v[9]  += mk * za.y; v[10] += mk * za.z; v[11] += mk * za.w;
            v[12] += mk * zb.x; v[13] += mk * zb.y; v[14] += mk * zb.z; v[15] += mk * zb.w;
        }
        float z0 = b_wl[0], z1 = b_wl[1];
#pragma unroll
        for (int j = 0; j < 8; ++j) {
            float g = bn_l1[j], b = bn_l1[8 + j], m = bn_l1[16 + j], va = bn_l1[24 + j];
            float y = (v[j] - m) * (g * rsqrtf(va + EPS)) + b;
            float sv = y / (1.f + expf(-y));
            z0 += w_wl[j] * sv;
            z1 += w_wl[16 + j] * sv;
            g = bn_l2[j]; b = bn_l2[8 + j]; m = bn_l2[16 + j]; va = bn_l2[24 + j];
            y = (v[8 + j] - m) * (g * rsqrtf(va + EPS)) + b;
            sv = y / (1.f + expf(-y));
            z0 += w_wl[8 + j] * sv;
            z1 += w_wl[24 + j] * sv;
        }
        lw0s[tid] = 1.f / (1.f + expf(z1 - z0));
    }
    __syncthreads();
    {   // pass2: u = CARAFE(z from L2)+b_up ; blend (i1 L2-hot) ; bf16 into lds2
        const float lw = lw0s[w], lw1 = 1.f - lw;
        const int wp = w0 + w;
        const int wq = wp >> 1;
        const int q = ((h & 1) << 1) | (wp & 1);
        const float* mrow = maskb + ((long)n * 1024 + hq * 32 + wq) * 36;
        float m9[9];
        const u16* zp[9];
#pragma unroll
        for (int k = 0; k < 9; ++k) {
            int dh = k / 3 - 1, dw = k - (k / 3) * 3 - 1;
            int gr = hq + dh, gc = wq + dw;
            bool ok = (gr >= 0 && gr < 32 && gc >= 0 && gc < 32);
            m9[k] = ok ? mrow[k * 4 + q] : 0.f;
            zp[k] = zbfT + ((long)n * 1024 +
                            (ok ? gr * 32 + gc : hq * 32 + wq)) * 256;
        }
        for (int ci = chunk * 32; ci < chunk * 32 + 32; ci += 8) {
            float uu[8];
            {
                float4 ba = *(const float4*)(bnp + 768 + ci);
                float4 bb = *(const float4*)(bnp + 768 + ci + 4);
                uu[0] = ba.x; uu[1] = ba.y; uu[2] = ba.z; uu[3] = ba.w;
                uu[4] = bb.x; uu[5] = bb.y; uu[6] = bb.z; uu[7] = bb.w;
            }
#pragma unroll
            for (int k = 0; k < 9; ++k) {
                uint4 vz = *(const uint4*)(zp[k] + ci);
                float mk = m9[k];
                uu[0] += mk * bf2f((u16)(vz.x & 0xffff));
                uu[1] += mk * bf2f((u16)(vz.x >> 16));
                uu[2] += mk * bf2f((u16)(vz.y & 0xffff));
                uu[3] += mk * bf2f((u16)(vz.y >> 16));
                uu[4] += mk * bf2f((u16)(vz.z & 0xffff));
                uu[5] += mk * bf2f((u16)(vz.z >> 16));
                uu[6] += mk * bf2f((u16)(vz.w & 0xffff));
                uu[7] += mk * bf2f((u16)(vz.w >> 16));
            }
            unsigned o0 = (unsigned)f2bf(i1[(long)ci * 4096] * lw + uu[0] * lw1)
                        | ((unsigned)f2bf(i1[(long)(ci + 1) * 4096] * lw + uu[1] * lw1) << 16);
            unsigned o1 = (unsigned)f2bf(i1[(long)(ci + 2) * 4096] * lw + uu[2] * lw1)
                        | ((unsigned)f2bf(i1[(long)(ci + 3) * 4096] * lw + uu[3] * lw1) << 16);
            unsigned o2 = (unsigned)f2bf(i1[(long)(ci + 4) * 4096] * lw + uu[4] * lw1)
                        | ((unsigned)f2bf(i1[(long)(ci + 5) * 4096] * lw + uu[5] * lw1) << 16);
            unsigned o3 = (unsigned)f2bf(i1[(long)(ci + 6) * 4096] * lw + uu[6] * lw1)
                        | ((unsigned)f2bf(i1[(long)(ci + 7) * 4096] * lw + uu[7] * lw1) << 16);
            *(uint4*)(lds2 + w * 264 + ci) = make_uint4(o0, o1, o2, o3);
        }
    }
    __syncthreads();
    {   // transposed padded write
        const int px = tid >> 3, qd = tid & 7;
        const int pg = (h << 6) + w0 + px;
        long prow = (long)((pg >> 6) + 1) * 66 + (pg & 63) + 1;
        u16* drow = dst + (long)n * 4356 * 256 + prow * 256;
        const u16* lrow = lds2 + px * 264;
#pragma unroll
        for (int j = 0; j < 16; ++j) {
            int off = j * 16 + qd * 2;
            *(unsigned*)(drow + off) = *(const unsigned*)(lrow + off);
        }
    }
}

// ---------------- K7: m97 GEMM — post-barrier 2-deep A staging (round-15 proven) ----------------
template<int KCC, int NT, bool PADDED>
__global__ __launch_bounds__(256, 2) void gemm_m97_kernel(
    const u16* __restrict__ A,      // [NT][256][KCC] bf16
    const u16* __restrict__ B,      // per image [rows][KCC] bf16
    const float* __restrict__ scale, const float* __restrict__ shift,
    float* __restrict__ C, long strideB, long strideC, int silu)
{
    constexpr int RROWS = PADDED ? 264 : 128;
    constexpr int BUNITS = RROWS * 4;
    constexpr int NKX = KCC / 32;
    constexpr int S = NKX * NT;
    __shared__ __align__(16) u16 lsA[3][128 * 32];
    __shared__ __align__(16) u16 lsB[2][RROWS * 32];
    const int n = blockIdx.z;
    const u16* Bn = B + (long)n * strideB;
    float* Cn = C + (long)n * strideC;
    const int tid = threadIdx.x;
    const int lane = tid & 63;
    const int wid = tid >> 6;
    const int mw = wid >> 1, nw = wid & 1;
    const int lr = lane & 15, lk = lane >> 4;
    const int rowBase = blockIdx.y * 128;
    const int colBase = blockIdx.x * 128;
    const int g0 = PADDED ? (colBase >> 6) * 66 : colBase;

    STAGE_B(lsB[0], 0);
    STAGE_A(lsA[0], 0, 0);
    STAGE_A(lsA[1], (NT > 1 ? 1 : 0), (NT > 1 ? 0 : 1));

    const int aswz = (lk ^ ((lr >> 1) & 3)) << 3;
    int aoff[4];
#pragma unroll
    for (int mf = 0; mf < 4; ++mf)
        aoff[mf] = (mw * 64 + mf * 16 + lr) * 32 + aswz;

    f32x4 acc[4][4] = {};
    for (int kx = 0; kx < NKX; ++kx) {
        const u16* lb = lsB[kx & 1];
#pragma unroll
        for (int t = 0; t < NT; ++t) {
            const int s = kx * NT + t;
            if (s == S - 1) { VMCNT(0); } else { VMCNT(2); }
            __builtin_amdgcn_s_barrier();
            asm volatile("" ::: "memory");
            if (s + 2 < S) {
                const int s2 = s + 2;
                const int kx2 = s2 / NT;
                const int t2 = s2 - kx2 * NT;
                STAGE_A(lsA[s2 % 3], t2, kx2);
            }
            if (t == 0 && kx + 1 < NKX) STAGE_B(lsB[(kx + 1) & 1], kx + 1);

            const u16* la = lsA[s % 3];
            bf16x8 af[4], bfr[4];
#pragma unroll
            for (int mf = 0; mf < 4; ++mf)
                af[mf] = *(const bf16x8*)(la + aoff[mf]);
            int rb;
            if (PADDED) {
                int dh = t / 3 - 1, dw = t - (t / 3) * 3 - 1;
                rb = (nw + dh + 1) * 66 + dw + 1 + lr;
            } else {
                rb = nw * 64 + lr;
            }
            const int bswz = (lk ^ ((rb >> 1) & 3)) << 3;
#pragma unroll
            for (int nf = 0; nf < 4; ++nf)
                bfr[nf] = *(const bf16x8*)(lb + (rb + nf * 16) * 32 + bswz);
#pragma unroll
            for (int mf = 0; mf < 4; ++mf)
#pragma unroll
                for (int nf = 0; nf < 4; ++nf)
                    acc[mf][nf] = __builtin_amdgcn_mfma_f32_16x16x32_bf16(
                        af[mf], bfr[nf], acc[mf][nf], 0, 0, 0);
        }
    }

#pragma unroll
    for (int mf = 0; mf < 4; ++mf) {
#pragma unroll
        for (int reg = 0; reg < 4; ++reg) {
            int co = rowBase + mw * 64 + mf * 16 + lk * 4 + reg;
            float sc = scale[co], sh = shift[co];
#pragma unroll
            for (int nf = 0; nf < 4; ++nf) {
                int col = colBase + nw * 64 + nf * 16 + lr;
                float y = acc[mf][nf][reg] * sc + sh;
                if (silu) y = y / (1.f + expf(-y));
                Cn[(long)co * 4096 + col] = y;
            }
        }
    }
}

// ---------------- prep kernels ----------------
__global__ __launch_bounds__(256) void prep_w_kernel(
    const float* __restrict__ w_conv, const float* __restrict__ w_up,
    const float* __restrict__ w_enc, const float* __restrict__ w_down,
    u16* __restrict__ wT, u16* __restrict__ wupT, u16* __restrict__ wencT,
    u16* __restrict__ wdT)
{
    int gid = blockIdx.x * 256 + threadIdx.x;
    if (gid < 589824) {             // wT[t][co][ci] = w_conv[co][ci][t]
        int t = gid >> 16;
        int co = (gid >> 8) & 255;
        int ci = gid & 255;
        wT[gid] = f2bf(w_conv[(co * 256 + ci) * 9 + t]);
    }
    if (gid < 131072) wupT[gid] = f2bf(w_up[gid]);
    if (gid < 73728) {              // wencT[t][co<64][ci] (zeros co>=36)
        int t = gid >> 13;
        int co = (gid >> 7) & 63;
        int ci = gid & 127;
        wencT[gid] = (co < 36) ? f2bf(w_enc[(co * 128 + ci) * 9 + t]) : (u16)0;
    }
    if (gid < 65536) wdT[gid] = f2bf(w_down[gid]);
}

__global__ void prep_bn_kernel(const float* __restrict__ bn_conv,
                               const float* __restrict__ b_up,
                               const float* __restrict__ w_l2,
                               float* __restrict__ bnp, float* __restrict__ wl2T)
{
    int i = threadIdx.x;            // 256
    float g = bn_conv[i], b = bn_conv[256 + i], m = bn_conv[512 + i], v = bn_conv[768 + i];
    float sc = g * rsqrtf(v + EPS);
    bnp[i] = sc;
    bnp[256 + i] = b - m * sc;
    bnp[768 + i] = b_up[i];
    if (i < 8) {                    // c2[j] = w_l2[j] . b_up
        float s = 0.f;
        for (int co = 0; co < 256; ++co) s += w_l2[i * 256 + co] * b_up[co];
        bnp[512 + i] = s;
    }
#pragma unroll
    for (int j = 0; j < 8; ++j)     // wl2T[co][j]
        wl2T[i * 8 + j] = w_l2[j * 256 + i];
}

extern "C" void kernel_launch(void* const* d_in, const int* in_sizes, int n_in,
                              void* d_out, int out_size, void* d_ws, size_t ws_size,
                              hipStream_t stream)
{
    const float* input1 = (const float*)d_in[0];
    const float* input2 = (const float*)d_in[1];
    const float* w_down = (const float*)d_in[2];
    const float* b_down = (const float*)d_in[3];
    const float* w_enc  = (const float*)d_in[4];
    const float* b_enc  = (const float*)d_in[5];
    const float* w_up   = (const float*)d_in[6];
    const float* b_up   = (const float*)d_in[7];
    const float* w_l1   = (const float*)d_in[8];
    const float* bn_l1  = (const float*)d_in[9];
    const float* w_l2   = (const float*)d_in[10];
    const float* bn_l2  = (const float*)d_in[11];
    const float* w_wl   = (const float*)d_in[12];
    const float* b_wl   = (const float*)d_in[13];
    const float* w_conv = (const float*)d_in[14];
    const float* bn_conv= (const float*)d_in[15];
    float* out = (float*)d_out;

    // workspace layout (float units). ~37 MB total.
    float* ws     = (float*)d_ws;
    float* ktTf   = ws;                      //   591,872 f : ktT bf16 [n][1156][128]
    float* wencTf = ktTf + 591872;           //    36,864 f
    float* maskb  = wencTf + 36864;          //   294,912 f
    float* in2Tf  = maskb + 294912;          // 2,097,152 f : in2T bf16 [n][1024][512]
    float* zbfTf  = in2Tf + 2097152;         // 1,048,576 f : zbfT bf16 [n][1024][256]
    float* zwT    = zbfTf + 1048576;         //    65,536 f : [n][1024][8] fp32
    float* ftbf   = zwT + 65536;             // 4,460,544 f : fusedT bf16 [n][4356][256]
    float* wTf    = ftbf + 4460544;          //   294,912 f
    float* wupTf  = wTf + 294912;            //    65,536 f
    float* wdTf   = wupTf + 65536;           //    32,768 f
    float* wl2T   = wdTf + 32768;            //     2,048 f
    float* bnp    = wl2T + 2048;             //     1,024 f
    u16* ktT      = (u16*)ktTf;
    u16* wencT    = (u16*)wencTf;
    u16* in2T     = (u16*)in2Tf;
    u16* zbfT     = (u16*)zbfTf;
    u16* ftb      = (u16*)ftbf;
    u16* wT       = (u16*)wTf;
    u16* wupT     = (u16*)wupTf;
    u16* wdT      = (u16*)wdTf;

    // prep (independent)
    prep_w_kernel<<<dim3(2304), 256, 0, stream>>>(w_conv, w_up, w_enc, w_down,
                                                  wT, wupT, wencT, wdT);
    prep_bn_kernel<<<dim3(1), 256, 0, stream>>>(bn_conv, b_up, w_l2, bnp, wl2T);
    border_zero_kernel<<<dim3(326), 256, 0, stream>>>(ftb, ktT);

    // in2T (feeds lowres_gemm)
    in2t_kernel<<<dim3(16, 8), 256, 0, stream>>>(input2, in2T);

    // merged lowres GEMM: zbfT (y<2) + ktT (y==2)
    lowres_gemm_kernel<<<dim3(8, 3, 8), 256, 0, stream>>>(
        wupT, wdT, in2T, b_down, zbfT, ktT);

    // mask pipeline: enc conv + in-register softmax -> maskb
    enc_softmax_kernel<<<dim3(64, 8), 64, 0, stream>>>(wencT, ktT, b_enc, maskb);

    // zw
    zw_kernel<<<dim3(2048), 256, 0, stream>>>(zbfT, wl2T, zwT);

    // merged level-attention + CARAFE + blend -> fusedT (z from L2, no staging)
    carafe_fuse_blend_kernel<<<dim3(128, 8), 256, 0, stream>>>(
        input1, zbfT, zwT, maskb, bnp, w_l1, bn_l1, bn_l2, w_wl, b_wl, ftb);

    // K7: final conv + BN + SiLU
    gemm_m97_kernel<256, 9, true><<<dim3(32, 2, 8), 256, 0, stream>>>(
        wT, ftb, bnp, bnp + 256, out, 4356L * 256, 256L * 4096, 1);
}